// Round 14
// baseline (617.307 us; speedup 1.0000x reference)
//
#include <hip/hip_runtime.h>

typedef _Float16 f16x8 __attribute__((ext_vector_type(8)));
typedef _Float16 f16x4 __attribute__((ext_vector_type(4)));
typedef float    f32x4 __attribute__((ext_vector_type(4)));

#define THW 6272
#define CCH 1024
#define DI  512

__device__ __forceinline__ void gload16(const _Float16* g, _Float16* l)
{
    __builtin_amdgcn_global_load_lds(
        (const __attribute__((address_space(1))) void*)g,
        (__attribute__((address_space(3))) void*)l, 16, 0, 0);
}

// ---------------------------------------------------------------------------
// m97-structure NT GEMM (single-buffered R11 core, BN-parametrized):
// C[M,N] = alpha*A[M,K]*Bt[N,K]^T (+bias_m/bias_n). A,Bt row-major K-contig.
// BMxBN tile (BN in {128,256}), BK=64, 4 waves 2x2, wave tile (BM/2)x(BN/2),
// global_load_lds(16B) into linear LDS, 2 barriers/K-step, bijective XCD
// swizzle. Flat 1-D grid gx*gy*gz, gz = 2*NKS (n = zz&1, ks = zz>>1).
// Split-K: slice ks covers [ks*K, min(ks*K+K, Kfull)); C += zz*sCn.
// EXPP: write exp(val), per-(row,64col) partial sums -> psum[row*98 + chunk],
//       chunk = cbase + bx*(BN/64) + wc*NH + (nf>>2).
// GNP:  per-block (sum,sumsq) -> psum[wg*2].
// RSC:  scale val by row_scale[n*rows_ps + row].
// ---------------------------------------------------------------------------
template<typename OUT_T, int BM, int BN, bool BIAS_M, bool BIAS_N, bool EXPP,
         bool GNP, bool RSC>
__global__ __launch_bounds__(256, 4)
void gemm_nt(const _Float16* __restrict__ A, size_t lda, size_t sAn,
             const _Float16* __restrict__ Bt, size_t ldb, size_t sBn,
             OUT_T* __restrict__ C, size_t ldc, size_t sCn,
             int K, int Kfull, float alpha,
             const float* __restrict__ bias_m,
             const float* __restrict__ bias_n,
             float* __restrict__ psum,
             const float* __restrict__ row_scale,
             int rows_ps, int cbase,
             int gx, int gy)
{
    constexpr int MF = BM / 32;      // A row-frags per wave; A stage issues
    constexpr int NF = BN / 32;      // B col-frags per wave; B stage issues
    constexpr int NH = (NF + 3) / 4; // 64-col chunks per wave
    __shared__ _Float16 As[BM * 64];
    __shared__ _Float16 Bs[BN * 64];
    __shared__ float rs[4], rs2[4];
    const int tid  = threadIdx.x;
    const int lane = tid & 63;
    const int wave = tid >> 6;
    const int wr = wave >> 1, wc = wave & 1;

    // bijective chunked XCD swizzle (m204)
    const int nwg = gridDim.x;
    const int q = nwg >> 3, rr = nwg & 7;
    const int xcd = blockIdx.x & 7, seq = blockIdx.x >> 3;
    const int wg = (xcd < rr ? xcd * (q + 1) : rr * (q + 1) + (xcd - rr) * q) + seq;
    const int zz  = wg / (gx * gy);
    const int rem = wg - zz * gx * gy;
    const int by  = rem / gx, bx = rem - by * gx;
    const int n   = zz & 1;        // sample
    const int ks  = zz >> 1;       // K-split index

    const int koff = ks * K;
    const int klen = (Kfull - koff < K) ? (Kfull - koff) : K;

    A  += (size_t)n * sAn + (size_t)by * BM * lda + koff;
    Bt += (size_t)n * sBn + (size_t)bx * BN * ldb + koff;

    // unified staging: issue i covers rows [i*32, i*32+32), 16B/thread
    const _Float16* gA0 = A  + (size_t)(tid >> 3) * lda + (tid & 7) * 8;
    const _Float16* gB0 = Bt + (size_t)(tid >> 3) * ldb + (tid & 7) * 8;
    _Float16* lA0 = As + tid * 8;
    _Float16* lB0 = Bs + tid * 8;

    const int r  = lane & 15;
    const int kg = lane >> 4;

    f32x4 acc[MF][NF] = {};

    for (int kt = 0; kt < klen; kt += 64) {
#pragma unroll
        for (int i = 0; i < MF; i++)
            gload16(gA0 + (size_t)(i * 32) * lda, lA0 + i * 2048);
#pragma unroll
        for (int i = 0; i < NF; i++)
            gload16(gB0 + (size_t)(i * 32) * ldb, lB0 + i * 2048);
        gA0 += 64; gB0 += 64;
        __syncthreads();
#pragma unroll
        for (int kk = 0; kk < 2; kk++) {
            f16x8 af[MF], bf[NF];
#pragma unroll
            for (int mf = 0; mf < MF; mf++)
                af[mf] = *(const f16x8*)(As + (wr * (BM / 2) + mf * 16 + r) * 64 + kk * 32 + kg * 8);
#pragma unroll
            for (int nf = 0; nf < NF; nf++)
                bf[nf] = *(const f16x8*)(Bs + (wc * (BN / 2) + nf * 16 + r) * 64 + kk * 32 + kg * 8);
#pragma unroll
            for (int mf = 0; mf < MF; mf++)
#pragma unroll
                for (int nf = 0; nf < NF; nf++)
                    acc[mf][nf] = __builtin_amdgcn_mfma_f32_16x16x32_f16(
                        af[mf], bf[nf], acc[mf][nf], 0, 0, 0);
        }
        __syncthreads();
    }

    C += (size_t)zz * sCn;
    float gs = 0.f, gs2 = 0.f;

#pragma unroll
    for (int mf = 0; mf < MF; mf++) {
#pragma unroll
        for (int qi = 0; qi < 4; qi++) {
            size_t row = (size_t)by * BM + wr * (BM / 2) + mf * 16 + kg * 4 + qi;
            float bm = BIAS_M ? bias_m[row] : 0.f;
            float sc = RSC ? row_scale[(size_t)n * rows_ps + row] : 1.f;
            float rsum[NH];
#pragma unroll
            for (int h = 0; h < NH; h++) rsum[h] = 0.f;
#pragma unroll
            for (int nf = 0; nf < NF; nf++) {
                size_t col = (size_t)bx * BN + wc * (BN / 2) + nf * 16 + r;
                float val = acc[mf][nf][qi] * alpha + bm + (BIAS_N ? bias_n[col] : 0.f);
                if (EXPP) { val = __expf(val); rsum[nf >> 2] += val; }
                else if (RSC) val *= sc;
                if (GNP) { gs += val; gs2 += val * val; }
                C[row * ldc + col] = (OUT_T)val;
            }
            if (EXPP) {
#pragma unroll
                for (int h = 0; h < NH; h++) {
                    float s = rsum[h];
                    s += __shfl_xor(s, 1);
                    s += __shfl_xor(s, 2);
                    s += __shfl_xor(s, 4);
                    s += __shfl_xor(s, 8);
                    if (r == 0)
                        psum[((size_t)n * rows_ps + row) * 98
                             + cbase + bx * (BN / 64) + wc * NH + h] = s;
                }
            }
        }
    }
    if (GNP) {
        for (int o = 32; o; o >>= 1) {
            gs  += __shfl_xor(gs, o);
            gs2 += __shfl_xor(gs2, o);
        }
        if (lane == 0) { rs[wave] = gs; rs2[wave] = gs2; }
        __syncthreads();
        if (tid == 0) {
            psum[(size_t)wg * 2]     = rs[0] + rs[1] + rs[2] + rs[3];
            psum[(size_t)wg * 2 + 1] = rs2[0] + rs2[1] + rs2[2] + rs2[3];
        }
    }
}

// ---------------------------------------------------------------------------
// inv[row] = 1 / sum_chunks psum[row][0..97]
// ---------------------------------------------------------------------------
__global__ __launch_bounds__(256)
void rowsum_inv(const float* __restrict__ psum, float* __restrict__ inv, int nrows)
{
    int rI = blockIdx.x * 256 + threadIdx.x;
    if (rI < nrows) {
        const float* p = psum + (size_t)rI * 98;
        float s = 0.f;
#pragma unroll 7
        for (int i = 0; i < 98; i++) s += p[i];
        inv[rI] = 1.f / s;
    }
}

// ---------------------------------------------------------------------------
// Ot[n][t0+t][d] = f16( sum_{ks=0..3} Op[ks*2+n][t][d] )   (Op fp16, normalized)
// ---------------------------------------------------------------------------
__global__ __launch_bounds__(256)
void combine4(const _Float16* __restrict__ Op, _Float16* __restrict__ Ot,
              int tr, int t0)
{
    const int per_n8 = tr * 64;                 // f16x8 vectors per sample
    int idx = blockIdx.x * 256 + threadIdx.x;
    if (idx >= 2 * per_n8) return;
    int n = idx / per_n8;
    int rem = idx - n * per_n8;
    int t = rem >> 6, d8 = rem & 63;
    const size_t slice = (size_t)tr * 512;
    float o[8] = {};
#pragma unroll
    for (int ks = 0; ks < 4; ks++) {
        f16x8 v = *(const f16x8*)(Op + (size_t)(ks * 2 + n) * slice + (size_t)rem * 8);
#pragma unroll
        for (int j = 0; j < 8; j++) o[j] += (float)v[j];
    }
    f16x8 w;
#pragma unroll
    for (int j = 0; j < 8; j++) w[j] = (_Float16)o[j];
    *(f16x8*)(Ot + ((size_t)(n * THW + t0 + t) * DI + d8 * 8)) = w;
}

// ---------------------------------------------------------------------------
__global__ __launch_bounds__(256)
void pack_weights(const float* __restrict__ wt, const float* __restrict__ wp,
                  const float* __restrict__ wg, const float* __restrict__ wo,
                  const float* __restrict__ bt, const float* __restrict__ bp,
                  _Float16* __restrict__ Wtp, _Float16* __restrict__ Wg,
                  _Float16* __restrict__ Wo, float* __restrict__ btp)
{
    int i = blockIdx.x * 256 + threadIdx.x;
    if (i < 512 * 1024) {
        Wtp[i]              = (_Float16)wt[i];
        Wtp[i + 512 * 1024] = (_Float16)wp[i];
        Wg[i]               = (_Float16)wg[i];
        Wo[i]               = (_Float16)wo[i];
    }
    if (i < 512) { btp[i] = bt[i]; btp[i + 512] = bp[i]; }
}

// ---------------------------------------------------------------------------
// xT[n, t, c] = f16(x[n, c, t])
// ---------------------------------------------------------------------------
__global__ __launch_bounds__(256)
void transpose_cast(const float* __restrict__ x, _Float16* __restrict__ xT)
{
    __shared__ float tile[32][33];
    const int n  = blockIdx.z;
    const int t0 = blockIdx.x * 32;
    const int c0 = blockIdx.y * 32;
    const int tx = threadIdx.x & 31, ty = threadIdx.x >> 5;
    const float* xp = x + ((size_t)n * CCH + c0) * THW + t0;
#pragma unroll
    for (int i = 0; i < 4; i++) {
        int c = ty + i * 8;
        tile[c][tx] = xp[(size_t)c * THW + tx];
    }
    __syncthreads();
    _Float16* op = xT + ((size_t)n * THW + t0) * CCH + c0;
#pragma unroll
    for (int i = 0; i < 4; i++) {
        int t = ty + i * 8;
        op[(size_t)t * CCH + tx] = (_Float16)tile[tx][t];
    }
}

// ---------------------------------------------------------------------------
// GroupNorm finalize from per-block partials + fused residual.
// ---------------------------------------------------------------------------
__global__ __launch_bounds__(256)
void reduce_final(const float* __restrict__ partials, float* __restrict__ stats, int nblk)
{
    const int n = blockIdx.x;
    float s = 0.f, s2 = 0.f;
    for (int i = threadIdx.x; i < nblk; i += 256) {
        s  += partials[((size_t)n * nblk + i) * 2];
        s2 += partials[((size_t)n * nblk + i) * 2 + 1];
    }
    for (int o = 32; o; o >>= 1) { s += __shfl_xor(s, o); s2 += __shfl_xor(s2, o); }
    __shared__ float rs[4], rs2[4];
    if ((threadIdx.x & 63) == 0) { rs[threadIdx.x >> 6] = s; rs2[threadIdx.x >> 6] = s2; }
    __syncthreads();
    if (threadIdx.x == 0) {
        float S1 = rs[0] + rs[1] + rs[2] + rs[3];
        float S2 = rs2[0] + rs2[1] + rs2[2] + rs2[3];
        const float invc = 1.f / ((float)CCH * (float)THW);
        float mean = S1 * invc;
        float var  = S2 * invc - mean * mean;
        stats[n * 2]     = mean;
        stats[n * 2 + 1] = rsqrtf(var + 1e-5f);
    }
}

__global__ __launch_bounds__(256)
void final_residual(const float* __restrict__ x, float* __restrict__ pc_out,
                    const float* __restrict__ stats, size_t total4)
{
    const size_t per_n4 = (size_t)CCH * THW / 4;
    for (size_t i = (size_t)blockIdx.x * 256 + threadIdx.x; i < total4;
         i += (size_t)gridDim.x * 256) {
        int n = (int)(i / per_n4);
        float mean = stats[n * 2], rstd = stats[n * 2 + 1];
        f32x4 xv = ((const f32x4*)x)[i];
        f32x4 pv = ((f32x4*)pc_out)[i];
        f32x4 ov;
#pragma unroll
        for (int j = 0; j < 4; j++) ov[j] = xv[j] + (pv[j] - mean) * rstd;
        ((f32x4*)pc_out)[i] = ov;
    }
}

// ---------------------------------------------------------------------------
extern "C" void kernel_launch(void* const* d_in, const int* in_sizes, int n_in,
                              void* d_out, int out_size, void* d_ws, size_t ws_size,
                              hipStream_t stream)
{
    const float* x  = (const float*)d_in[0];
    const float* wt = (const float*)d_in[1];
    const float* bt = (const float*)d_in[2];
    const float* wp = (const float*)d_in[3];
    const float* bp = (const float*)d_in[4];
    const float* wg = (const float*)d_in[5];
    const float* bg = (const float*)d_in[6];
    const float* wo = (const float*)d_in[7];
    const float* bo = (const float*)d_in[8];
    float* out = (float*)d_out;

    char* ws = (char*)d_ws;
    size_t off = 0;
    auto alloc = [&](size_t b) -> void* {
        off = (off + 255) & ~(size_t)255;
        void* p = ws + off;
        off += b;
        return p;
    };

    _Float16* Wtp = (_Float16*)alloc((size_t)1024 * 1024 * 2);
    _Float16* Wg  = (_Float16*)alloc((size_t)512 * 1024 * 2);
    _Float16* Wo  = (_Float16*)alloc((size_t)1024 * 512 * 2);
    float*    btp = (float*)alloc(1024 * 4);
    _Float16* xT  = (_Float16*)alloc((size_t)2 * THW * CCH * 2);
    _Float16* tpg = (_Float16*)alloc((size_t)2 * THW * 1024 * 2);  // [n][t][theta|phi]
    _Float16* g   = (_Float16*)alloc((size_t)2 * DI * THW * 2);    // [n][d][t]
    _Float16* Ot  = (_Float16*)alloc((size_t)2 * THW * DI * 2);    // [n][t][d]
    float*    gnp   = (float*)alloc((size_t)1568 * 2 * 4);         // out-GEMM block stats
    float*    stats = (float*)alloc(4 * 4);

    // exp(S) fp16 in ws; PV split-K=4 fp16 NORMALIZED partials in d_out.
    const size_t tile_bytes = (size_t)2 * 128 * (THW * 2 + 98 * 4 + 4);
    size_t avail = (ws_size > off + 256) ? ws_size - off - 256 : 0;
    int tiles_fit = (int)(avail / tile_bytes);
    if (tiles_fit < 1) tiles_fit = 1;
    if (tiles_fit > 49) tiles_fit = 49;
    int nch = (49 + tiles_fit - 1) / tiles_fit;
    int tpc = (49 + nch - 1) / nch;

    _Float16* S    = (_Float16*)alloc((size_t)2 * tpc * 128 * THW * 2);
    float*    psum = (float*)alloc((size_t)2 * tpc * 128 * 98 * 4);
    float*    inv  = (float*)alloc((size_t)2 * tpc * 128 * 4);
    _Float16* Opart = (_Float16*)out;   // [8][tpc*128][512] fp16, fits 51.4 MB

    const size_t sXT = (size_t)THW * CCH;
    const size_t sG  = (size_t)DI * THW;

    pack_weights<<<2048, 256, 0, stream>>>(wt, wp, wg, wo, bt, bp, Wtp, Wg, Wo, btp);
    transpose_cast<<<dim3(THW / 32, CCH / 32, 2), 256, 0, stream>>>(x, xT);

    // theta|phi (t-major): tpg[t, m] = sum_c xT[t,c]*Wtp[m,c] + btp[m]
    gemm_nt<_Float16, 128, 128, false, true, false, false, false><<<8 * 49 * 2, 256, 0, stream>>>(
        xT, CCH, sXT, Wtp, CCH, 0, tpg, 1024, sXT, CCH, CCH, 1.f,
        nullptr, btp, nullptr, nullptr, 0, 0, 8, 49);

    // g (d-major): g[d, t] = sum_c Wg[d,c]*xT[t,c] + bg[d]
    gemm_nt<_Float16, 64, 128, true, false, false, false, false><<<49 * 8 * 2, 256, 0, stream>>>(
        Wg, CCH, 0, xT, CCH, sXT, g, THW, sG, CCH, CCH, 1.f,
        bg, nullptr, nullptr, nullptr, 0, 0, 49, 8);

    const float scale = 0.044194173824159216f;  // 512^-0.5
    for (int ch = 0; ch < nch; ch++) {
        int tile0 = ch * tpc;
        int tiles = (49 - tile0 < tpc) ? (49 - tile0) : tpc;
        size_t t0 = (size_t)tile0 * 128;
        int tchRows = tiles * 128;

        // expS[t,p] main: p in [0,6144), BN=256 (24 col-tiles); psum chunks 0..95
        gemm_nt<_Float16, 128, 256, false, false, true, false, false><<<24 * tiles * 2, 256, 0, stream>>>(
            tpg + t0 * 1024, 1024, sXT, tpg + 512, 1024, sXT,
            S, THW, (size_t)tchRows * THW, DI, DI, scale,
            nullptr, nullptr, psum, nullptr, tchRows, 0, 24, tiles);

        // expS[t,p] tail: p in [6144,6272), BN=128; psum chunks 96..97
        gemm_nt<_Float16, 128, 128, false, false, true, false, false><<<1 * tiles * 2, 256, 0, stream>>>(
            tpg + t0 * 1024, 1024, sXT, tpg + 512 + (size_t)6144 * 1024, 1024, sXT,
            S + 6144, THW, (size_t)tchRows * THW, DI, DI, scale,
            nullptr, nullptr, psum, nullptr, tchRows, 96, 1, tiles);

        rowsum_inv<<<(2 * tchRows + 255) / 256, 256, 0, stream>>>(psum, inv, 2 * tchRows);

        // Opart[zz][t][d] = inv[t] * sum_{p in split ks} expS[t,p]*g[d,p]
        // split-K=4 (1600x3+1472), BN=256 (d: 2 col-tiles), normalized fp16
        gemm_nt<_Float16, 128, 256, false, false, false, false, true><<<2 * tiles * 8, 256, 0, stream>>>(
            S, THW, (size_t)tchRows * THW, g, THW, sG,
            Opart, DI, (size_t)tchRows * DI, 1600, THW, 1.f,
            nullptr, nullptr, nullptr, inv, tchRows, 0, 2, tiles);

        // Ot[t,d] = f16( sum_ks Opart[ks*2+n][t][d] )
        combine4<<<(tchRows * 128 + 255) / 256, 256, 0, stream>>>(
            Opart, Ot, tchRows, (int)t0);
    }

    // Pc[c,t] = sum_d Wo[c,d]*Ot[t,d] + bo[c]; emits per-block GroupNorm stats
    gemm_nt<float, 128, 128, true, false, false, true, false><<<49 * 8 * 2, 256, 0, stream>>>(
        Wo, DI, 0, Ot, DI, sG, out, THW, (size_t)CCH * THW, DI, DI, 1.f,
        bo, nullptr, gnp, nullptr, 0, 0, 49, 8);

    reduce_final<<<2, 256, 0, stream>>>(gnp, stats, 392);
    final_residual<<<2048, 256, 0, stream>>>(x, out, stats, (size_t)2 * CCH * THW / 4);
}

// Round 15
// 388.290 us; speedup vs baseline: 1.5898x; 1.5898x over previous
//
#include <hip/hip_runtime.h>

typedef _Float16 f16x8 __attribute__((ext_vector_type(8)));
typedef _Float16 f16x4 __attribute__((ext_vector_type(4)));
typedef float    f32x4 __attribute__((ext_vector_type(4)));

#define THW 6272
#define CCH 1024
#define DI  512

__device__ __forceinline__ void gload16(const _Float16* g, _Float16* l)
{
    __builtin_amdgcn_global_load_lds(
        (const __attribute__((address_space(1))) void*)g,
        (__attribute__((address_space(3))) void*)l, 16, 0, 0);
}

// ---------------------------------------------------------------------------
// m97-structure NT GEMM (single-buffered R11 core — measured local optimum):
// C[M,N] = alpha*A[M,K]*Bt[N,K]^T (+bias_m/bias_n). A,Bt row-major K-contig.
// BMx128 tile, BK=64, 4 waves, global_load_lds(16B) into linear LDS,
// 2 barriers/K-step, bijective XCD swizzle. Flat 1-D grid gx*gy*gz,
// gz = 2*NKS (sample-fastest: n = zz&1, ks = zz>>1).
// Split-K: slice ks covers [ks*K, min(ks*K+K, Kfull)); C += zz*sCn.
// EXPP: write exp(val), emit per-(row,64col) partial sums to psum.
// GNP:  emit per-block (sum, sumsq) into psum[wg*2].
// RSC:  scale val by row_scale[n*rows_ps + row].
// Tested-and-regressed variants (do not retry): BM=64 (R4), BK=64 dbuf (R6),
// LDS-roundtrip epilogue (R9), transposed-store epilogue (R10/R12),
// 8-wave blocks (R13), BN=256 (R14, VGPR cliff).
// ---------------------------------------------------------------------------
template<typename OUT_T, int BM, bool BIAS_M, bool BIAS_N, bool EXPP, bool GNP, bool RSC>
__global__ __launch_bounds__(256, 4)
void gemm_nt(const _Float16* __restrict__ A, size_t lda, size_t sAn,
             const _Float16* __restrict__ Bt, size_t ldb, size_t sBn,
             OUT_T* __restrict__ C, size_t ldc, size_t sCn,
             int K, int Kfull, float alpha,
             const float* __restrict__ bias_m,
             const float* __restrict__ bias_n,
             float* __restrict__ psum,
             const float* __restrict__ row_scale,
             int rows_ps,
             int gx, int gy)
{
    constexpr int MF = BM / 32;
    __shared__ _Float16 As[BM * 64];
    __shared__ _Float16 Bs[128 * 64];
    __shared__ float rs[4], rs2[4];
    const int tid  = threadIdx.x;
    const int lane = tid & 63;
    const int wave = tid >> 6;
    const int wr = wave >> 1, wc = wave & 1;

    // bijective chunked XCD swizzle (m204)
    const int nwg = gridDim.x;
    const int q = nwg >> 3, rr = nwg & 7;
    const int xcd = blockIdx.x & 7, seq = blockIdx.x >> 3;
    const int wg = (xcd < rr ? xcd * (q + 1) : rr * (q + 1) + (xcd - rr) * q) + seq;
    const int zz  = wg / (gx * gy);
    const int rem = wg - zz * gx * gy;
    const int by  = rem / gx, bx = rem - by * gx;
    const int n   = zz & 1;        // sample
    const int ks  = zz >> 1;       // K-split index

    const int koff = ks * K;
    const int klen = (Kfull - koff < K) ? (Kfull - koff) : K;

    A  += (size_t)n * sAn + (size_t)by * BM * lda + koff;
    Bt += (size_t)n * sBn + (size_t)bx * 128 * ldb + koff;

    const int srow = lane >> 3, sk = (lane & 7) * 8;
    const _Float16* gA = A  + (size_t)(wave * (MF * 8) + srow) * lda + sk;
    const _Float16* gB = Bt + (size_t)(wave * 32 + srow) * ldb + sk;
    _Float16* lA = As + wave * (MF * 512) + lane * 8;
    _Float16* lB = Bs + wave * 2048 + lane * 8;

    const int r  = lane & 15;
    const int kg = lane >> 4;

    f32x4 acc[MF][4] = {};

    for (int kt = 0; kt < klen; kt += 64) {
#pragma unroll
        for (int i = 0; i < MF; i++)
            gload16(gA + (size_t)(i * 8) * lda, lA + i * 512);
#pragma unroll
        for (int i = 0; i < 4; i++)
            gload16(gB + (size_t)(i * 8) * ldb, lB + i * 512);
        gA += 64; gB += 64;
        __syncthreads();
#pragma unroll
        for (int kk = 0; kk < 2; kk++) {
            f16x8 af[MF], bf[4];
#pragma unroll
            for (int mf = 0; mf < MF; mf++)
                af[mf] = *(const f16x8*)(As + (wr * (BM / 2) + mf * 16 + r) * 64 + kk * 32 + kg * 8);
#pragma unroll
            for (int nf = 0; nf < 4; nf++)
                bf[nf] = *(const f16x8*)(Bs + (wc * 64 + nf * 16 + r) * 64 + kk * 32 + kg * 8);
#pragma unroll
            for (int mf = 0; mf < MF; mf++)
#pragma unroll
                for (int nf = 0; nf < 4; nf++)
                    acc[mf][nf] = __builtin_amdgcn_mfma_f32_16x16x32_f16(
                        af[mf], bf[nf], acc[mf][nf], 0, 0, 0);
        }
        __syncthreads();
    }

    C += (size_t)zz * sCn;
    float gs = 0.f, gs2 = 0.f;

#pragma unroll
    for (int mf = 0; mf < MF; mf++) {
#pragma unroll
        for (int qi = 0; qi < 4; qi++) {
            size_t row = (size_t)by * BM + wr * (BM / 2) + mf * 16 + kg * 4 + qi;
            float bm = BIAS_M ? bias_m[row] : 0.f;
            float sc = RSC ? row_scale[(size_t)n * rows_ps + row] : 1.f;
            float rsum = 0.f;
#pragma unroll
            for (int nf = 0; nf < 4; nf++) {
                size_t col = (size_t)bx * 128 + wc * 64 + nf * 16 + r;
                float val = acc[mf][nf][qi] * alpha + bm + (BIAS_N ? bias_n[col] : 0.f);
                if (EXPP) { val = __expf(val); rsum += val; }
                else if (RSC) val *= sc;
                if (GNP) { gs += val; gs2 += val * val; }
                C[row * ldc + col] = (OUT_T)val;
            }
            if (EXPP) {
                rsum += __shfl_xor(rsum, 1);
                rsum += __shfl_xor(rsum, 2);
                rsum += __shfl_xor(rsum, 4);
                rsum += __shfl_xor(rsum, 8);
                if (r == 0)
                    psum[((size_t)n * rows_ps + row) * 98 + bx * 2 + wc] = rsum;
            }
        }
    }
    if (GNP) {
        for (int o = 32; o; o >>= 1) {
            gs  += __shfl_xor(gs, o);
            gs2 += __shfl_xor(gs2, o);
        }
        if (lane == 0) { rs[wave] = gs; rs2[wave] = gs2; }
        __syncthreads();
        if (tid == 0) {
            psum[(size_t)wg * 2]     = rs[0] + rs[1] + rs[2] + rs[3];
            psum[(size_t)wg * 2 + 1] = rs2[0] + rs2[1] + rs2[2] + rs2[3];
        }
    }
}

// ---------------------------------------------------------------------------
// inv[row] = 1 / sum_chunks psum[row][0..97]
// ---------------------------------------------------------------------------
__global__ __launch_bounds__(256)
void rowsum_inv(const float* __restrict__ psum, float* __restrict__ inv, int nrows)
{
    int rI = blockIdx.x * 256 + threadIdx.x;
    if (rI < nrows) {
        const float* p = psum + (size_t)rI * 98;
        float s = 0.f;
#pragma unroll 7
        for (int i = 0; i < 98; i++) s += p[i];
        inv[rI] = 1.f / s;
    }
}

// ---------------------------------------------------------------------------
// Ot[n][t0+t][d] = f16( sum_{ks=0..3} Op[ks*2+n][t][d] )   (Op fp16, normalized)
// ---------------------------------------------------------------------------
__global__ __launch_bounds__(256)
void combine4(const _Float16* __restrict__ Op, _Float16* __restrict__ Ot,
              int tr, int t0)
{
    const int per_n8 = tr * 64;                 // f16x8 vectors per sample
    int idx = blockIdx.x * 256 + threadIdx.x;
    if (idx >= 2 * per_n8) return;
    int n = idx / per_n8;
    int rem = idx - n * per_n8;
    int t = rem >> 6, d8 = rem & 63;
    const size_t slice = (size_t)tr * 512;
    float o[8] = {};
#pragma unroll
    for (int ks = 0; ks < 4; ks++) {
        f16x8 v = *(const f16x8*)(Op + (size_t)(ks * 2 + n) * slice + (size_t)rem * 8);
#pragma unroll
        for (int j = 0; j < 8; j++) o[j] += (float)v[j];
    }
    f16x8 w;
#pragma unroll
    for (int j = 0; j < 8; j++) w[j] = (_Float16)o[j];
    *(f16x8*)(Ot + ((size_t)(n * THW + t0 + t) * DI + d8 * 8)) = w;
}

// ---------------------------------------------------------------------------
__global__ __launch_bounds__(256)
void pack_weights(const float* __restrict__ wt, const float* __restrict__ wp,
                  const float* __restrict__ wg, const float* __restrict__ wo,
                  const float* __restrict__ bt, const float* __restrict__ bp,
                  _Float16* __restrict__ Wtp, _Float16* __restrict__ Wg,
                  _Float16* __restrict__ Wo, float* __restrict__ btp)
{
    int i = blockIdx.x * 256 + threadIdx.x;
    if (i < 512 * 1024) {
        Wtp[i]              = (_Float16)wt[i];
        Wtp[i + 512 * 1024] = (_Float16)wp[i];
        Wg[i]               = (_Float16)wg[i];
        Wo[i]               = (_Float16)wo[i];
    }
    if (i < 512) { btp[i] = bt[i]; btp[i + 512] = bp[i]; }
}

// ---------------------------------------------------------------------------
// xT[n, t, c] = f16(x[n, c, t])  — 64x64 tile, f32 coalesced loads,
// f16x8 vector stores (16B/lane), padded LDS.
// ---------------------------------------------------------------------------
__global__ __launch_bounds__(256)
void transpose_cast(const float* __restrict__ x, _Float16* __restrict__ xT)
{
    __shared__ float tile[64][65];
    const int n  = blockIdx.z;
    const int t0 = blockIdx.x * 64;
    const int c0 = blockIdx.y * 64;
    const int tid = threadIdx.x;
    const float* xp = x + ((size_t)n * CCH + c0) * THW + t0;
#pragma unroll
    for (int i = 0; i < 16; i++) {
        int v = tid + i * 256;          // 0..4095
        int c = v >> 6, t = v & 63;
        tile[t][c] = xp[(size_t)c * THW + t];
    }
    __syncthreads();
    _Float16* op = xT + ((size_t)n * THW + t0) * CCH + c0;
#pragma unroll
    for (int i = 0; i < 2; i++) {
        int v = tid + i * 256;          // 0..511
        int t = v >> 3, c8 = (v & 7) * 8;
        f16x8 o;
#pragma unroll
        for (int j = 0; j < 8; j++) o[j] = (_Float16)tile[t][c8 + j];
        *(f16x8*)(op + (size_t)t * CCH + c8) = o;
    }
}

// ---------------------------------------------------------------------------
// GroupNorm finalize from per-block partials + fused residual.
// ---------------------------------------------------------------------------
__global__ __launch_bounds__(256)
void reduce_final(const float* __restrict__ partials, float* __restrict__ stats, int nblk)
{
    const int n = blockIdx.x;
    float s = 0.f, s2 = 0.f;
    for (int i = threadIdx.x; i < nblk; i += 256) {
        s  += partials[((size_t)n * nblk + i) * 2];
        s2 += partials[((size_t)n * nblk + i) * 2 + 1];
    }
    for (int o = 32; o; o >>= 1) { s += __shfl_xor(s, o); s2 += __shfl_xor(s2, o); }
    __shared__ float rs[4], rs2[4];
    if ((threadIdx.x & 63) == 0) { rs[threadIdx.x >> 6] = s; rs2[threadIdx.x >> 6] = s2; }
    __syncthreads();
    if (threadIdx.x == 0) {
        float S1 = rs[0] + rs[1] + rs[2] + rs[3];
        float S2 = rs2[0] + rs2[1] + rs2[2] + rs2[3];
        const float invc = 1.f / ((float)CCH * (float)THW);
        float mean = S1 * invc;
        float var  = S2 * invc - mean * mean;
        stats[n * 2]     = mean;
        stats[n * 2 + 1] = rsqrtf(var + 1e-5f);
    }
}

__global__ __launch_bounds__(256)
void final_residual(const float* __restrict__ x, float* __restrict__ pc_out,
                    const float* __restrict__ stats, size_t total4)
{
    const size_t per_n4 = (size_t)CCH * THW / 4;
    for (size_t i = (size_t)blockIdx.x * 256 + threadIdx.x; i < total4;
         i += (size_t)gridDim.x * 256) {
        int n = (int)(i / per_n4);
        float mean = stats[n * 2], rstd = stats[n * 2 + 1];
        f32x4 xv = ((const f32x4*)x)[i];
        f32x4 pv = ((f32x4*)pc_out)[i];
        f32x4 ov;
#pragma unroll
        for (int j = 0; j < 4; j++) ov[j] = xv[j] + (pv[j] - mean) * rstd;
        ((f32x4*)pc_out)[i] = ov;
    }
}

// ---------------------------------------------------------------------------
extern "C" void kernel_launch(void* const* d_in, const int* in_sizes, int n_in,
                              void* d_out, int out_size, void* d_ws, size_t ws_size,
                              hipStream_t stream)
{
    const float* x  = (const float*)d_in[0];
    const float* wt = (const float*)d_in[1];
    const float* bt = (const float*)d_in[2];
    const float* wp = (const float*)d_in[3];
    const float* bp = (const float*)d_in[4];
    const float* wg = (const float*)d_in[5];
    const float* bg = (const float*)d_in[6];
    const float* wo = (const float*)d_in[7];
    const float* bo = (const float*)d_in[8];
    float* out = (float*)d_out;

    char* ws = (char*)d_ws;
    size_t off = 0;
    auto alloc = [&](size_t b) -> void* {
        off = (off + 255) & ~(size_t)255;
        void* p = ws + off;
        off += b;
        return p;
    };

    _Float16* Wtp = (_Float16*)alloc((size_t)1024 * 1024 * 2);
    _Float16* Wg  = (_Float16*)alloc((size_t)512 * 1024 * 2);
    _Float16* Wo  = (_Float16*)alloc((size_t)1024 * 512 * 2);
    float*    btp = (float*)alloc(1024 * 4);
    _Float16* xT  = (_Float16*)alloc((size_t)2 * THW * CCH * 2);
    _Float16* tpg = (_Float16*)alloc((size_t)2 * THW * 1024 * 2);  // [n][t][theta|phi]
    _Float16* g   = (_Float16*)alloc((size_t)2 * DI * THW * 2);    // [n][d][t]
    _Float16* Ot  = (_Float16*)alloc((size_t)2 * THW * DI * 2);    // [n][t][d]
    float*    gnp   = (float*)alloc((size_t)1568 * 2 * 4);         // out-GEMM block stats
    float*    stats = (float*)alloc(4 * 4);

    // exp(S) fp16 in ws; PV split-K=4 fp16 NORMALIZED partials in d_out.
    const size_t tile_bytes = (size_t)2 * 128 * (THW * 2 + 98 * 4 + 4);
    size_t avail = (ws_size > off + 256) ? ws_size - off - 256 : 0;
    int tiles_fit = (int)(avail / tile_bytes);
    if (tiles_fit < 1) tiles_fit = 1;
    if (tiles_fit > 49) tiles_fit = 49;
    int nch = (49 + tiles_fit - 1) / tiles_fit;
    int tpc = (49 + nch - 1) / nch;

    _Float16* S    = (_Float16*)alloc((size_t)2 * tpc * 128 * THW * 2);
    float*    psum = (float*)alloc((size_t)2 * tpc * 128 * 98 * 4);
    float*    inv  = (float*)alloc((size_t)2 * tpc * 128 * 4);
    _Float16* Opart = (_Float16*)out;   // [8][tpc*128][512] fp16, fits 51.4 MB

    const size_t sXT = (size_t)THW * CCH;
    const size_t sG  = (size_t)DI * THW;

    pack_weights<<<2048, 256, 0, stream>>>(wt, wp, wg, wo, bt, bp, Wtp, Wg, Wo, btp);
    transpose_cast<<<dim3(THW / 64, CCH / 64, 2), 256, 0, stream>>>(x, xT);

    // theta|phi (t-major): tpg[t, m] = sum_c xT[t,c]*Wtp[m,c] + btp[m]
    gemm_nt<_Float16, 128, false, true, false, false, false><<<8 * 49 * 2, 256, 0, stream>>>(
        xT, CCH, sXT, Wtp, CCH, 0, tpg, 1024, sXT, CCH, CCH, 1.f,
        nullptr, btp, nullptr, nullptr, 0, 8, 49);

    // g (d-major): g[d, t] = sum_c Wg[d,c]*xT[t,c] + bg[d]
    gemm_nt<_Float16, 64, true, false, false, false, false><<<49 * 8 * 2, 256, 0, stream>>>(
        Wg, CCH, 0, xT, CCH, sXT, g, THW, sG, CCH, CCH, 1.f,
        bg, nullptr, nullptr, nullptr, 0, 49, 8);

    const float scale = 0.044194173824159216f;  // 512^-0.5
    for (int ch = 0; ch < nch; ch++) {
        int tile0 = ch * tpc;
        int tiles = (49 - tile0 < tpc) ? (49 - tile0) : tpc;
        size_t t0 = (size_t)tile0 * 128;
        int tchRows = tiles * 128;

        // expS[t,p] = exp(scale * sum_d theta[t,d]*phi[p,d]); psum partials
        gemm_nt<_Float16, 128, false, false, true, false, false><<<49 * tiles * 2, 256, 0, stream>>>(
            tpg + t0 * 1024, 1024, sXT, tpg + 512, 1024, sXT,
            S, THW, (size_t)tchRows * THW, DI, DI, scale,
            nullptr, nullptr, psum, nullptr, tchRows, 49, tiles);

        rowsum_inv<<<(2 * tchRows + 255) / 256, 256, 0, stream>>>(psum, inv, 2 * tchRows);

        // Opart[zz][t][d] = inv[t] * sum_{p in split ks} expS[t,p]*g[d,p]
        // split-K=4 (uneven: 1600,1600,1600,1472), normalized fp16 partials
        gemm_nt<_Float16, 128, false, false, false, false, true><<<4 * tiles * 8, 256, 0, stream>>>(
            S, THW, (size_t)tchRows * THW, g, THW, sG,
            Opart, DI, (size_t)tchRows * DI, 1600, THW, 1.f,
            nullptr, nullptr, nullptr, inv, tchRows, 4, tiles);

        // Ot[t,d] = f16( sum_ks Opart[ks*2+n][t][d] )
        combine4<<<(tchRows * 128 + 255) / 256, 256, 0, stream>>>(
            Opart, Ot, tchRows, (int)t0);
    }

    // Pc[c,t] = sum_d Wo[c,d]*Ot[t,d] + bo[c]; emits per-block GroupNorm stats
    gemm_nt<float, 128, true, false, false, true, false><<<49 * 8 * 2, 256, 0, stream>>>(
        Wo, DI, 0, Ot, DI, sG, out, THW, (size_t)CCH * THW, DI, DI, 1.f,
        bo, nullptr, gnp, nullptr, 0, 49, 8);

    reduce_final<<<2, 256, 0, stream>>>(gnp, stats, 392);
    final_residual<<<2048, 256, 0, stream>>>(x, out, stats, (size_t)2 * CCH * THW / 4);
}

// Round 16
// 380.973 us; speedup vs baseline: 1.6203x; 1.0192x over previous
//
#include <hip/hip_runtime.h>

typedef _Float16 f16x8 __attribute__((ext_vector_type(8)));
typedef _Float16 f16x4 __attribute__((ext_vector_type(4)));
typedef float    f32x4 __attribute__((ext_vector_type(4)));

#define THW 6272
#define CCH 1024
#define DI  512

__device__ __forceinline__ void gload16(const _Float16* g, _Float16* l)
{
    __builtin_amdgcn_global_load_lds(
        (const __attribute__((address_space(1))) void*)g,
        (__attribute__((address_space(3))) void*)l, 16, 0, 0);
}

// ---------------------------------------------------------------------------
// m97-structure NT GEMM (single-buffered R11 core — measured local optimum):
// C[M,N] = alpha*A[M,K]*Bt[N,K]^T (+bias_m/bias_n). A,Bt row-major K-contig.
// BMx128 tile, BK=64, 4 waves, global_load_lds(16B) into linear LDS,
// 2 barriers/K-step, bijective XCD swizzle. Flat 1-D grid gx*gy*gz,
// gz = 2*NKS (sample-fastest: n = zz&1, ks = zz>>1).
// Split-K: slice ks covers [ks*K, min(ks*K+K, Kfull)); C += zz*sCn.
// stile>0: decode (by,bx) in stile x stile super-tiles (L2 working-set
// tiling; requires gx%stile==0 && gy%stile==0), else bx-fastest.
// EXPP: write exp(val), emit per-(row,64col) partial sums to psum.
// GNP:  emit per-block (sum, sumsq) into psum[wg*2].
// RSC:  scale val by row_scale[n*rows_ps + row].
// Tested-and-regressed variants (do not retry): BM=64 (R4), BK=64 dbuf (R6),
// LDS-roundtrip epilogue (R9), transposed-store epilogue (R10/R12),
// 8-wave blocks (R13), BN=256 (R14, VGPR cliff).
// ---------------------------------------------------------------------------
template<typename OUT_T, int BM, bool BIAS_M, bool BIAS_N, bool EXPP, bool GNP, bool RSC>
__global__ __launch_bounds__(256, 4)
void gemm_nt(const _Float16* __restrict__ A, size_t lda, size_t sAn,
             const _Float16* __restrict__ Bt, size_t ldb, size_t sBn,
             OUT_T* __restrict__ C, size_t ldc, size_t sCn,
             int K, int Kfull, float alpha,
             const float* __restrict__ bias_m,
             const float* __restrict__ bias_n,
             float* __restrict__ psum,
             const float* __restrict__ row_scale,
             int rows_ps, int stile,
             int gx, int gy)
{
    constexpr int MF = BM / 32;
    __shared__ _Float16 As[BM * 64];
    __shared__ _Float16 Bs[128 * 64];
    __shared__ float rs[4], rs2[4];
    const int tid  = threadIdx.x;
    const int lane = tid & 63;
    const int wave = tid >> 6;
    const int wr = wave >> 1, wc = wave & 1;

    // bijective chunked XCD swizzle (m204)
    const int nwg = gridDim.x;
    const int q = nwg >> 3, rr = nwg & 7;
    const int xcd = blockIdx.x & 7, seq = blockIdx.x >> 3;
    const int wg = (xcd < rr ? xcd * (q + 1) : rr * (q + 1) + (xcd - rr) * q) + seq;
    const int zz  = wg / (gx * gy);
    const int rem = wg - zz * gx * gy;
    int by, bx;
    if (stile > 0) {
        // super-tile decode: consecutive wgs fill a stile x stile block of
        // (by,bx) tiles, supers walk scol-fastest (shared by-panel in L2)
        const int per = stile * stile;
        const int sgx = gx / stile;
        const int sid = rem / per, wi = rem - sid * per;
        const int srow = sid / sgx, scol = sid - srow * sgx;
        const int wrow = wi / stile;
        by = srow * stile + wrow;
        bx = scol * stile + (wi - wrow * stile);
    } else {
        by = rem / gx; bx = rem - by * gx;
    }
    const int n   = zz & 1;        // sample
    const int ks  = zz >> 1;       // K-split index

    const int koff = ks * K;
    const int klen = (Kfull - koff < K) ? (Kfull - koff) : K;

    A  += (size_t)n * sAn + (size_t)by * BM * lda + koff;
    Bt += (size_t)n * sBn + (size_t)bx * 128 * ldb + koff;

    const int srow = lane >> 3, sk = (lane & 7) * 8;
    const _Float16* gA = A  + (size_t)(wave * (MF * 8) + srow) * lda + sk;
    const _Float16* gB = Bt + (size_t)(wave * 32 + srow) * ldb + sk;
    _Float16* lA = As + wave * (MF * 512) + lane * 8;
    _Float16* lB = Bs + wave * 2048 + lane * 8;

    const int r  = lane & 15;
    const int kg = lane >> 4;

    f32x4 acc[MF][4] = {};

    for (int kt = 0; kt < klen; kt += 64) {
#pragma unroll
        for (int i = 0; i < MF; i++)
            gload16(gA + (size_t)(i * 8) * lda, lA + i * 512);
#pragma unroll
        for (int i = 0; i < 4; i++)
            gload16(gB + (size_t)(i * 8) * ldb, lB + i * 512);
        gA += 64; gB += 64;
        __syncthreads();
#pragma unroll
        for (int kk = 0; kk < 2; kk++) {
            f16x8 af[MF], bf[4];
#pragma unroll
            for (int mf = 0; mf < MF; mf++)
                af[mf] = *(const f16x8*)(As + (wr * (BM / 2) + mf * 16 + r) * 64 + kk * 32 + kg * 8);
#pragma unroll
            for (int nf = 0; nf < 4; nf++)
                bf[nf] = *(const f16x8*)(Bs + (wc * 64 + nf * 16 + r) * 64 + kk * 32 + kg * 8);
#pragma unroll
            for (int mf = 0; mf < MF; mf++)
#pragma unroll
                for (int nf = 0; nf < 4; nf++)
                    acc[mf][nf] = __builtin_amdgcn_mfma_f32_16x16x32_f16(
                        af[mf], bf[nf], acc[mf][nf], 0, 0, 0);
        }
        __syncthreads();
    }

    C += (size_t)zz * sCn;
    float gs = 0.f, gs2 = 0.f;

#pragma unroll
    for (int mf = 0; mf < MF; mf++) {
#pragma unroll
        for (int qi = 0; qi < 4; qi++) {
            size_t row = (size_t)by * BM + wr * (BM / 2) + mf * 16 + kg * 4 + qi;
            float bm = BIAS_M ? bias_m[row] : 0.f;
            float sc = RSC ? row_scale[(size_t)n * rows_ps + row] : 1.f;
            float rsum = 0.f;
#pragma unroll
            for (int nf = 0; nf < 4; nf++) {
                size_t col = (size_t)bx * 128 + wc * 64 + nf * 16 + r;
                float val = acc[mf][nf][qi] * alpha + bm + (BIAS_N ? bias_n[col] : 0.f);
                if (EXPP) { val = __expf(val); rsum += val; }
                else if (RSC) val *= sc;
                if (GNP) { gs += val; gs2 += val * val; }
                C[row * ldc + col] = (OUT_T)val;
            }
            if (EXPP) {
                rsum += __shfl_xor(rsum, 1);
                rsum += __shfl_xor(rsum, 2);
                rsum += __shfl_xor(rsum, 4);
                rsum += __shfl_xor(rsum, 8);
                if (r == 0)
                    psum[((size_t)n * rows_ps + row) * 98 + bx * 2 + wc] = rsum;
            }
        }
    }
    if (GNP) {
        for (int o = 32; o; o >>= 1) {
            gs  += __shfl_xor(gs, o);
            gs2 += __shfl_xor(gs2, o);
        }
        if (lane == 0) { rs[wave] = gs; rs2[wave] = gs2; }
        __syncthreads();
        if (tid == 0) {
            psum[(size_t)wg * 2]     = rs[0] + rs[1] + rs[2] + rs[3];
            psum[(size_t)wg * 2 + 1] = rs2[0] + rs2[1] + rs2[2] + rs2[3];
        }
    }
}

// ---------------------------------------------------------------------------
// inv[row] = 1 / sum_chunks psum[row][0..97]
// ---------------------------------------------------------------------------
__global__ __launch_bounds__(256)
void rowsum_inv(const float* __restrict__ psum, float* __restrict__ inv, int nrows)
{
    int rI = blockIdx.x * 256 + threadIdx.x;
    if (rI < nrows) {
        const float* p = psum + (size_t)rI * 98;
        float s = 0.f;
#pragma unroll 7
        for (int i = 0; i < 98; i++) s += p[i];
        inv[rI] = 1.f / s;
    }
}

// ---------------------------------------------------------------------------
// Ot[n][t0+t][d] = f16( sum_{ks=0..3} Op[ks*2+n][t][d] )   (Op fp16, normalized)
// ---------------------------------------------------------------------------
__global__ __launch_bounds__(256)
void combine4(const _Float16* __restrict__ Op, _Float16* __restrict__ Ot,
              int tr, int t0)
{
    const int per_n8 = tr * 64;                 // f16x8 vectors per sample
    int idx = blockIdx.x * 256 + threadIdx.x;
    if (idx >= 2 * per_n8) return;
    int n = idx / per_n8;
    int rem = idx - n * per_n8;
    int t = rem >> 6, d8 = rem & 63;
    const size_t slice = (size_t)tr * 512;
    float o[8] = {};
#pragma unroll
    for (int ks = 0; ks < 4; ks++) {
        f16x8 v = *(const f16x8*)(Op + (size_t)(ks * 2 + n) * slice + (size_t)rem * 8);
#pragma unroll
        for (int j = 0; j < 8; j++) o[j] += (float)v[j];
    }
    f16x8 w;
#pragma unroll
    for (int j = 0; j < 8; j++) w[j] = (_Float16)o[j];
    *(f16x8*)(Ot + ((size_t)(n * THW + t0 + t) * DI + d8 * 8)) = w;
}

// ---------------------------------------------------------------------------
__global__ __launch_bounds__(256)
void pack_weights(const float* __restrict__ wt, const float* __restrict__ wp,
                  const float* __restrict__ wg, const float* __restrict__ wo,
                  const float* __restrict__ bt, const float* __restrict__ bp,
                  _Float16* __restrict__ Wtp, _Float16* __restrict__ Wg,
                  _Float16* __restrict__ Wo, float* __restrict__ btp)
{
    int i = blockIdx.x * 256 + threadIdx.x;
    if (i < 512 * 1024) {
        Wtp[i]              = (_Float16)wt[i];
        Wtp[i + 512 * 1024] = (_Float16)wp[i];
        Wg[i]               = (_Float16)wg[i];
        Wo[i]               = (_Float16)wo[i];
    }
    if (i < 512) { btp[i] = bt[i]; btp[i + 512] = bp[i]; }
}

// ---------------------------------------------------------------------------
// xT[n, t, c] = f16(x[n, c, t])  — 64x64 tile, f32 coalesced loads,
// f16x8 vector stores (16B/lane), padded LDS.
// ---------------------------------------------------------------------------
__global__ __launch_bounds__(256)
void transpose_cast(const float* __restrict__ x, _Float16* __restrict__ xT)
{
    __shared__ float tile[64][65];
    const int n  = blockIdx.z;
    const int t0 = blockIdx.x * 64;
    const int c0 = blockIdx.y * 64;
    const int tid = threadIdx.x;
    const float* xp = x + ((size_t)n * CCH + c0) * THW + t0;
#pragma unroll
    for (int i = 0; i < 16; i++) {
        int v = tid + i * 256;          // 0..4095
        int c = v >> 6, t = v & 63;
        tile[t][c] = xp[(size_t)c * THW + t];
    }
    __syncthreads();
    _Float16* op = xT + ((size_t)n * THW + t0) * CCH + c0;
#pragma unroll
    for (int i = 0; i < 2; i++) {
        int v = tid + i * 256;          // 0..511
        int t = v >> 3, c8 = (v & 7) * 8;
        f16x8 o;
#pragma unroll
        for (int j = 0; j < 8; j++) o[j] = (_Float16)tile[t][c8 + j];
        *(f16x8*)(op + (size_t)t * CCH + c8) = o;
    }
}

// ---------------------------------------------------------------------------
// GroupNorm finalize from per-block partials + fused residual.
// ---------------------------------------------------------------------------
__global__ __launch_bounds__(256)
void reduce_final(const float* __restrict__ partials, float* __restrict__ stats, int nblk)
{
    const int n = blockIdx.x;
    float s = 0.f, s2 = 0.f;
    for (int i = threadIdx.x; i < nblk; i += 256) {
        s  += partials[((size_t)n * nblk + i) * 2];
        s2 += partials[((size_t)n * nblk + i) * 2 + 1];
    }
    for (int o = 32; o; o >>= 1) { s += __shfl_xor(s, o); s2 += __shfl_xor(s2, o); }
    __shared__ float rs[4], rs2[4];
    if ((threadIdx.x & 63) == 0) { rs[threadIdx.x >> 6] = s; rs2[threadIdx.x >> 6] = s2; }
    __syncthreads();
    if (threadIdx.x == 0) {
        float S1 = rs[0] + rs[1] + rs[2] + rs[3];
        float S2 = rs2[0] + rs2[1] + rs2[2] + rs2[3];
        const float invc = 1.f / ((float)CCH * (float)THW);
        float mean = S1 * invc;
        float var  = S2 * invc - mean * mean;
        stats[n * 2]     = mean;
        stats[n * 2 + 1] = rsqrtf(var + 1e-5f);
    }
}

// out[i] = x[i] + (pc16[i] - mean) * rstd   (pc16 fp16, x/out fp32)
__global__ __launch_bounds__(256)
void final_residual(const float* __restrict__ x, const _Float16* __restrict__ pc16,
                    float* __restrict__ outp, const float* __restrict__ stats,
                    size_t total4)
{
    const size_t per_n4 = (size_t)CCH * THW / 4;
    for (size_t i = (size_t)blockIdx.x * 256 + threadIdx.x; i < total4;
         i += (size_t)gridDim.x * 256) {
        int n = (int)(i / per_n4);
        float mean = stats[n * 2], rstd = stats[n * 2 + 1];
        f32x4 xv = ((const f32x4*)x)[i];
        f16x4 pv = ((const f16x4*)pc16)[i];
        f32x4 ov;
#pragma unroll
        for (int j = 0; j < 4; j++) ov[j] = xv[j] + ((float)pv[j] - mean) * rstd;
        ((f32x4*)outp)[i] = ov;
    }
}

// ---------------------------------------------------------------------------
extern "C" void kernel_launch(void* const* d_in, const int* in_sizes, int n_in,
                              void* d_out, int out_size, void* d_ws, size_t ws_size,
                              hipStream_t stream)
{
    const float* x  = (const float*)d_in[0];
    const float* wt = (const float*)d_in[1];
    const float* bt = (const float*)d_in[2];
    const float* wp = (const float*)d_in[3];
    const float* bp = (const float*)d_in[4];
    const float* wg = (const float*)d_in[5];
    const float* bg = (const float*)d_in[6];
    const float* wo = (const float*)d_in[7];
    const float* bo = (const float*)d_in[8];
    float* out = (float*)d_out;

    char* ws = (char*)d_ws;
    size_t off = 0;
    auto alloc = [&](size_t b) -> void* {
        off = (off + 255) & ~(size_t)255;
        void* p = ws + off;
        off += b;
        return p;
    };

    _Float16* Wtp = (_Float16*)alloc((size_t)1024 * 1024 * 2);
    _Float16* Wg  = (_Float16*)alloc((size_t)512 * 1024 * 2);
    _Float16* Wo  = (_Float16*)alloc((size_t)1024 * 512 * 2);
    float*    btp = (float*)alloc(1024 * 4);
    _Float16* xT  = (_Float16*)alloc((size_t)2 * THW * CCH * 2);
    _Float16* tpg = (_Float16*)alloc((size_t)2 * THW * 1024 * 2);  // [n][t][theta|phi]
    _Float16* g   = (_Float16*)alloc((size_t)2 * DI * THW * 2);    // [n][d][t]
    _Float16* Ot  = (_Float16*)alloc((size_t)2 * THW * DI * 2);    // [n][t][d]
    float*    gnp   = (float*)alloc((size_t)1568 * 2 * 4);         // out-GEMM block stats
    float*    stats = (float*)alloc(4 * 4);

    // exp(S) fp16 in ws; PV split-K=4 fp16 NORMALIZED partials in d_out.
    const size_t tile_bytes = (size_t)2 * 128 * (THW * 2 + 98 * 4 + 4);
    size_t avail = (ws_size > off + 256) ? ws_size - off - 256 : 0;
    int tiles_fit = (int)(avail / tile_bytes);
    if (tiles_fit < 1) tiles_fit = 1;
    if (tiles_fit > 49) tiles_fit = 49;
    int nch = (49 + tiles_fit - 1) / tiles_fit;
    int tpc = (49 + nch - 1) / nch;

    _Float16* S    = (_Float16*)alloc((size_t)2 * tpc * 128 * THW * 2);
    float*    psum = (float*)alloc((size_t)2 * tpc * 128 * 98 * 4);
    float*    inv  = (float*)alloc((size_t)2 * tpc * 128 * 4);
    _Float16* Opart = (_Float16*)out;   // [8][tpc*128][512] fp16, fits 51.4 MB
    _Float16* Pc16  = tpg;              // tpg dead after S-GEMM; 25.7 MB reuse

    const size_t sXT = (size_t)THW * CCH;
    const size_t sG  = (size_t)DI * THW;

    pack_weights<<<2048, 256, 0, stream>>>(wt, wp, wg, wo, bt, bp, Wtp, Wg, Wo, btp);
    transpose_cast<<<dim3(THW / 64, CCH / 64, 2), 256, 0, stream>>>(x, xT);

    // theta|phi (t-major): tpg[t, m] = sum_c xT[t,c]*Wtp[m,c] + btp[m]
    gemm_nt<_Float16, 128, false, true, false, false, false><<<8 * 49 * 2, 256, 0, stream>>>(
        xT, CCH, sXT, Wtp, CCH, 0, tpg, 1024, sXT, CCH, CCH, 1.f,
        nullptr, btp, nullptr, nullptr, 0, 0, 8, 49);

    // g (d-major): g[d, t] = sum_c Wg[d,c]*xT[t,c] + bg[d]
    gemm_nt<_Float16, 64, true, false, false, false, false><<<49 * 8 * 2, 256, 0, stream>>>(
        Wg, CCH, 0, xT, CCH, sXT, g, THW, sG, CCH, CCH, 1.f,
        bg, nullptr, nullptr, nullptr, 0, 0, 49, 8);

    const float scale = 0.044194173824159216f;  // 512^-0.5
    for (int ch = 0; ch < nch; ch++) {
        int tile0 = ch * tpc;
        int tiles = (49 - tile0 < tpc) ? (49 - tile0) : tpc;
        size_t t0 = (size_t)tile0 * 128;
        int tchRows = tiles * 128;
        int stile = (tiles % 7 == 0) ? 7 : 0;   // 7x7 L2 super-tiling

        // expS[t,p] = exp(scale * sum_d theta[t,d]*phi[p,d]); psum partials
        gemm_nt<_Float16, 128, false, false, true, false, false><<<49 * tiles * 2, 256, 0, stream>>>(
            tpg + t0 * 1024, 1024, sXT, tpg + 512, 1024, sXT,
            S, THW, (size_t)tchRows * THW, DI, DI, scale,
            nullptr, nullptr, psum, nullptr, tchRows, stile, 49, tiles);

        rowsum_inv<<<(2 * tchRows + 255) / 256, 256, 0, stream>>>(psum, inv, 2 * tchRows);

        // Opart[zz][t][d] = inv[t] * sum_{p in split ks} expS[t,p]*g[d,p]
        // split-K=4 (uneven: 1600,1600,1600,1472), normalized fp16 partials
        gemm_nt<_Float16, 128, false, false, false, false, true><<<4 * tiles * 8, 256, 0, stream>>>(
            S, THW, (size_t)tchRows * THW, g, THW, sG,
            Opart, DI, (size_t)tchRows * DI, 1600, THW, 1.f,
            nullptr, nullptr, nullptr, inv, tchRows, 0, 4, tiles);

        // Ot[t,d] = f16( sum_ks Opart[ks*2+n][t][d] )
        combine4<<<(tchRows * 128 + 255) / 256, 256, 0, stream>>>(
            Opart, Ot, tchRows, (int)t0);
    }

    // Pc16[c,t] = f16(sum_d Wo[c,d]*Ot[t,d] + bo[c]); per-block GroupNorm stats
    gemm_nt<_Float16, 128, true, false, false, true, false><<<49 * 8 * 2, 256, 0, stream>>>(
        Wo, DI, 0, Ot, DI, sG, Pc16, THW, (size_t)CCH * THW, DI, DI, 1.f,
        bo, nullptr, gnp, nullptr, 0, 0, 49, 8);

    reduce_final<<<2, 256, 0, stream>>>(gnp, stats, 392);
    final_residual<<<2048, 256, 0, stream>>>(x, Pc16, out, stats, (size_t)2 * CCH * THW / 4);
}

// Round 18
// 380.971 us; speedup vs baseline: 1.6204x; 1.0000x over previous
//
#include <hip/hip_runtime.h>

typedef _Float16 f16x8 __attribute__((ext_vector_type(8)));
typedef _Float16 f16x4 __attribute__((ext_vector_type(4)));
typedef float    f32x4 __attribute__((ext_vector_type(4)));

#define THW 6272
#define CCH 1024
#define DI  512

__device__ __forceinline__ void gload16(const _Float16* g, _Float16* l)
{
    __builtin_amdgcn_global_load_lds(
        (const __attribute__((address_space(1))) void*)g,
        (__attribute__((address_space(3))) void*)l, 16, 0, 0);
}

// ---------------------------------------------------------------------------
// NT GEMM, BK=32 double-buffered counted-vmcnt pipeline (T3/T4 minimum):
// C[M,N] = alpha*A[M,K]*Bt[N,K]^T (+bias). A,Bt row-major K-contig.
// BMx128 tile, 4 waves, LDS 2buf x (BM+128)x32 fp16 (32KB @BM=128 - same
// residency as R16 single-buf). Loop body 2x-unrolled (all NT even) so
// buffer indices are compile-time. Per step: STAGE(next tile, other buf)
// -> s_waitcnt vmcnt(ISS) (newest ISS loads stay IN FLIGHT across barrier)
// -> s_barrier -> 16 MFMA -> s_barrier. Never drains vmcnt mid-loop.
// ISS = BM/64 + 2 (A issues + B issues per stage).
// Flat grid gx*gy*gz, gz = 2*NKS (n=zz&1, ks=zz>>1); split-K slice
// [ks*K, min(ks*K+K,Kfull)); C += zz*sCn. stile>0: LxL super-tile decode.
// EXPP: val = exp2(val) (alpha premultiplied by log2e), per-(row,64col)
// partial sums -> psum. GNP: per-block (sum,sumsq). RSC: row scale.
// Regressed variants (do not retry): BM=64-for-PV (R4), BK=64 dbuf 64KB (R6),
// LDS/transposed epilogues (R9/R10/R12), 8-wave (R13), BN=256 (R14).
// ---------------------------------------------------------------------------
template<typename OUT_T, int BM, bool BIAS_M, bool BIAS_N, bool EXPP, bool GNP, bool RSC>
__global__ __launch_bounds__(256, 4)
void gemm_nt(const _Float16* __restrict__ A, size_t lda, size_t sAn,
             const _Float16* __restrict__ Bt, size_t ldb, size_t sBn,
             OUT_T* __restrict__ C, size_t ldc, size_t sCn,
             int K, int Kfull, float alpha,
             const float* __restrict__ bias_m,
             const float* __restrict__ bias_n,
             float* __restrict__ psum,
             const float* __restrict__ row_scale,
             int rows_ps, int stile,
             int gx, int gy)
{
    constexpr int MF   = BM / 32;    // A 16-row frags per wave
    constexpr int AISS = BM / 64;    // A stage issues per tile
    constexpr int ASZ  = BM * 32;    // A elems per buffer
    __shared__ _Float16 As[2 * ASZ];
    __shared__ _Float16 Bs[2 * 4096];
    __shared__ float rs[4], rs2[4];
    const int tid  = threadIdx.x;
    const int lane = tid & 63;
    const int wave = tid >> 6;
    const int wr = wave >> 1, wc = wave & 1;

    // bijective chunked XCD swizzle (m204)
    const int nwg = gridDim.x;
    const int q = nwg >> 3, rr = nwg & 7;
    const int xcd = blockIdx.x & 7, seq = blockIdx.x >> 3;
    const int wg = (xcd < rr ? xcd * (q + 1) : rr * (q + 1) + (xcd - rr) * q) + seq;
    const int zz  = wg / (gx * gy);
    const int rem = wg - zz * gx * gy;
    int by, bx;
    if (stile > 0) {
        const int per = stile * stile;
        const int sgx = gx / stile;
        const int sid = rem / per, wi = rem - sid * per;
        const int srow = sid / sgx, scol = sid - srow * sgx;
        const int wrow = wi / stile;
        by = srow * stile + wrow;
        bx = scol * stile + (wi - wrow * stile);
    } else {
        by = rem / gx; bx = rem - by * gx;
    }
    const int n   = zz & 1;
    const int ks  = zz >> 1;

    const int koff = ks * K;
    const int klen = (Kfull - koff < K) ? (Kfull - koff) : K;

    A  += (size_t)n * sAn + (size_t)by * BM * lda + koff;
    Bt += (size_t)n * sBn + (size_t)bx * 128 * ldb + koff;

    // per-thread staging offsets (BK=32: 4 vec8/row)
    const int v0 = tid, v1 = tid + 256;
    const size_t aG0 = (size_t)(v0 >> 2) * lda + (v0 & 3) * 8;
    const size_t aG1 = (size_t)(v1 >> 2) * lda + (v1 & 3) * 8;
    const size_t bG0 = (size_t)(v0 >> 2) * ldb + (v0 & 3) * 8;
    const size_t bG1 = (size_t)(v1 >> 2) * ldb + (v1 & 3) * 8;
    const int lo0 = v0 * 8, lo1 = v1 * 8;

    const int r  = lane & 15;
    const int kg = lane >> 4;

    f32x4 acc[MF][4] = {};

    auto STAGE = [&](int t, int b) {
        const _Float16* a  = A  + (size_t)t * 32;
        const _Float16* bt = Bt + (size_t)t * 32;
        gload16(a + aG0, As + b * ASZ + lo0);
        if constexpr (AISS == 2) gload16(a + aG1, As + b * ASZ + lo1);
        gload16(bt + bG0, Bs + b * 4096 + lo0);
        gload16(bt + bG1, Bs + b * 4096 + lo1);
    };
    auto WAITN = [&]() {
        if constexpr (AISS == 2) asm volatile("s_waitcnt vmcnt(4)" ::: "memory");
        else                     asm volatile("s_waitcnt vmcnt(3)" ::: "memory");
    };
    auto COMPUTE = [&](int b) {
        f16x8 af[MF], bf[4];
#pragma unroll
        for (int mf = 0; mf < MF; mf++)
            af[mf] = *(const f16x8*)(As + b * ASZ + (wr * (BM / 2) + mf * 16 + r) * 32 + kg * 8);
#pragma unroll
        for (int nf = 0; nf < 4; nf++)
            bf[nf] = *(const f16x8*)(Bs + b * 4096 + (wc * 64 + nf * 16 + r) * 32 + kg * 8);
#pragma unroll
        for (int mf = 0; mf < MF; mf++)
#pragma unroll
            for (int nf = 0; nf < 4; nf++)
                acc[mf][nf] = __builtin_amdgcn_mfma_f32_16x16x32_f16(
                    af[mf], bf[nf], acc[mf][nf], 0, 0, 0);
    };

    const int NT = klen >> 5;        // all call-site NT values are even
    STAGE(0, 0);
    for (int it = 0; it < NT; it += 2) {
        STAGE(it + 1, 1);
        WAITN();
        __builtin_amdgcn_s_barrier();
        COMPUTE(0);
        __builtin_amdgcn_s_barrier();
        if (it + 2 < NT) {
            STAGE(it + 2, 0);
            WAITN();
        } else {
            asm volatile("s_waitcnt vmcnt(0)" ::: "memory");
        }
        __builtin_amdgcn_s_barrier();
        COMPUTE(1);
        __builtin_amdgcn_s_barrier();
    }

    C += (size_t)zz * sCn;
    float gs = 0.f, gs2 = 0.f;

#pragma unroll
    for (int mf = 0; mf < MF; mf++) {
#pragma unroll
        for (int qi = 0; qi < 4; qi++) {
            size_t row = (size_t)by * BM + wr * (BM / 2) + mf * 16 + kg * 4 + qi;
            float bm = BIAS_M ? bias_m[row] : 0.f;
            float sc = RSC ? row_scale[(size_t)n * rows_ps + row] : 1.f;
            float rsum = 0.f;
#pragma unroll
            for (int nf = 0; nf < 4; nf++) {
                size_t col = (size_t)bx * 128 + wc * 64 + nf * 16 + r;
                float val = acc[mf][nf][qi] * alpha + bm + (BIAS_N ? bias_n[col] : 0.f);
                if (EXPP) { val = exp2f(val); rsum += val; }
                else if (RSC) val *= sc;
                if (GNP) { gs += val; gs2 += val * val; }
                C[row * ldc + col] = (OUT_T)val;
            }
            if (EXPP) {
                rsum += __shfl_xor(rsum, 1);
                rsum += __shfl_xor(rsum, 2);
                rsum += __shfl_xor(rsum, 4);
                rsum += __shfl_xor(rsum, 8);
                if (r == 0)
                    psum[((size_t)n * rows_ps + row) * 98 + bx * 2 + wc] = rsum;
            }
        }
    }
    if (GNP) {
        for (int o = 32; o; o >>= 1) {
            gs  += __shfl_xor(gs, o);
            gs2 += __shfl_xor(gs2, o);
        }
        if (lane == 0) { rs[wave] = gs; rs2[wave] = gs2; }
        __syncthreads();
        if (tid == 0) {
            psum[(size_t)wg * 2]     = rs[0] + rs[1] + rs[2] + rs[3];
            psum[(size_t)wg * 2 + 1] = rs2[0] + rs2[1] + rs2[2] + rs2[3];
        }
    }
}

// ---------------------------------------------------------------------------
// inv[row] = 1 / sum_chunks psum[row][0..97]
// ---------------------------------------------------------------------------
__global__ __launch_bounds__(256)
void rowsum_inv(const float* __restrict__ psum, float* __restrict__ inv, int nrows)
{
    int rI = blockIdx.x * 256 + threadIdx.x;
    if (rI < nrows) {
        const float* p = psum + (size_t)rI * 98;
        float s = 0.f;
#pragma unroll 7
        for (int i = 0; i < 98; i++) s += p[i];
        inv[rI] = 1.f / s;
    }
}

// ---------------------------------------------------------------------------
// Ot[n][t0+t][d] = f16( sum_{ks=0..3} Op[ks*2+n][t][d] )   (Op fp16, normalized)
// ---------------------------------------------------------------------------
__global__ __launch_bounds__(256)
void combine4(const _Float16* __restrict__ Op, _Float16* __restrict__ Ot,
              int tr, int t0)
{
    const int per_n8 = tr * 64;
    int idx = blockIdx.x * 256 + threadIdx.x;
    if (idx >= 2 * per_n8) return;
    int n = idx / per_n8;
    int rem = idx - n * per_n8;
    int t = rem >> 6, d8 = rem & 63;
    const size_t slice = (size_t)tr * 512;
    float o[8] = {};
#pragma unroll
    for (int ks = 0; ks < 4; ks++) {
        f16x8 v = *(const f16x8*)(Op + (size_t)(ks * 2 + n) * slice + (size_t)rem * 8);
#pragma unroll
        for (int j = 0; j < 8; j++) o[j] += (float)v[j];
    }
    f16x8 w;
#pragma unroll
    for (int j = 0; j < 8; j++) w[j] = (_Float16)o[j];
    *(f16x8*)(Ot + ((size_t)(n * THW + t0 + t) * DI + d8 * 8)) = w;
}

// ---------------------------------------------------------------------------
__global__ __launch_bounds__(256)
void pack_weights(const float* __restrict__ wt, const float* __restrict__ wp,
                  const float* __restrict__ wg, const float* __restrict__ wo,
                  const float* __restrict__ bt, const float* __restrict__ bp,
                  _Float16* __restrict__ Wtp, _Float16* __restrict__ Wg,
                  _Float16* __restrict__ Wo, float* __restrict__ btp)
{
    int i = blockIdx.x * 256 + threadIdx.x;
    if (i < 512 * 1024) {
        Wtp[i]              = (_Float16)wt[i];
        Wtp[i + 512 * 1024] = (_Float16)wp[i];
        Wg[i]               = (_Float16)wg[i];
        Wo[i]               = (_Float16)wo[i];
    }
    if (i < 512) { btp[i] = bt[i]; btp[i + 512] = bp[i]; }
}

// ---------------------------------------------------------------------------
// xT[n, t, c] = f16(x[n, c, t])  — 64x64 tile, f16x8 vector stores.
// ---------------------------------------------------------------------------
__global__ __launch_bounds__(256)
void transpose_cast(const float* __restrict__ x, _Float16* __restrict__ xT)
{
    __shared__ float tile[64][65];
    const int n  = blockIdx.z;
    const int t0 = blockIdx.x * 64;
    const int c0 = blockIdx.y * 64;
    const int tid = threadIdx.x;
    const float* xp = x + ((size_t)n * CCH + c0) * THW + t0;
#pragma unroll
    for (int i = 0; i < 16; i++) {
        int v = tid + i * 256;
        int c = v >> 6, t = v & 63;
        tile[t][c] = xp[(size_t)c * THW + t];
    }
    __syncthreads();
    _Float16* op = xT + ((size_t)n * THW + t0) * CCH + c0;
#pragma unroll
    for (int i = 0; i < 2; i++) {
        int v = tid + i * 256;
        int t = v >> 3, c8 = (v & 7) * 8;
        f16x8 o;
#pragma unroll
        for (int j = 0; j < 8; j++) o[j] = (_Float16)tile[t][c8 + j];
        *(f16x8*)(op + (size_t)t * CCH + c8) = o;
    }
}

// ---------------------------------------------------------------------------
// GroupNorm finalize from per-block partials + fused residual.
// ---------------------------------------------------------------------------
__global__ __launch_bounds__(256)
void reduce_final(const float* __restrict__ partials, float* __restrict__ stats, int nblk)
{
    const int n = blockIdx.x;
    float s = 0.f, s2 = 0.f;
    for (int i = threadIdx.x; i < nblk; i += 256) {
        s  += partials[((size_t)n * nblk + i) * 2];
        s2 += partials[((size_t)n * nblk + i) * 2 + 1];
    }
    for (int o = 32; o; o >>= 1) { s += __shfl_xor(s, o); s2 += __shfl_xor(s2, o); }
    __shared__ float rs[4], rs2[4];
    if ((threadIdx.x & 63) == 0) { rs[threadIdx.x >> 6] = s; rs2[threadIdx.x >> 6] = s2; }
    __syncthreads();
    if (threadIdx.x == 0) {
        float S1 = rs[0] + rs[1] + rs[2] + rs[3];
        float S2 = rs2[0] + rs2[1] + rs2[2] + rs2[3];
        const float invc = 1.f / ((float)CCH * (float)THW);
        float mean = S1 * invc;
        float var  = S2 * invc - mean * mean;
        stats[n * 2]     = mean;
        stats[n * 2 + 1] = rsqrtf(var + 1e-5f);
    }
}

// out[i] = x[i] + (pc16[i] - mean) * rstd
__global__ __launch_bounds__(256)
void final_residual(const float* __restrict__ x, const _Float16* __restrict__ pc16,
                    float* __restrict__ outp, const float* __restrict__ stats,
                    size_t total4)
{
    const size_t per_n4 = (size_t)CCH * THW / 4;
    for (size_t i = (size_t)blockIdx.x * 256 + threadIdx.x; i < total4;
         i += (size_t)gridDim.x * 256) {
        int n = (int)(i / per_n4);
        float mean = stats[n * 2], rstd = stats[n * 2 + 1];
        f32x4 xv = ((const f32x4*)x)[i];
        f16x4 pv = ((const f16x4*)pc16)[i];
        f32x4 ov;
#pragma unroll
        for (int j = 0; j < 4; j++) ov[j] = xv[j] + ((float)pv[j] - mean) * rstd;
        ((f32x4*)outp)[i] = ov;
    }
}

// ---------------------------------------------------------------------------
extern "C" void kernel_launch(void* const* d_in, const int* in_sizes, int n_in,
                              void* d_out, int out_size, void* d_ws, size_t ws_size,
                              hipStream_t stream)
{
    const float* x  = (const float*)d_in[0];
    const float* wt = (const float*)d_in[1];
    const float* bt = (const float*)d_in[2];
    const float* wp = (const float*)d_in[3];
    const float* bp = (const float*)d_in[4];
    const float* wg = (const float*)d_in[5];
    const float* bg = (const float*)d_in[6];
    const float* wo = (const float*)d_in[7];
    const float* bo = (const float*)d_in[8];
    float* out = (float*)d_out;

    char* ws = (char*)d_ws;
    size_t off = 0;
    auto alloc = [&](size_t b) -> void* {
        off = (off + 255) & ~(size_t)255;
        void* p = ws + off;
        off += b;
        return p;
    };

    _Float16* Wtp = (_Float16*)alloc((size_t)1024 * 1024 * 2);
    _Float16* Wg  = (_Float16*)alloc((size_t)512 * 1024 * 2);
    _Float16* Wo  = (_Float16*)alloc((size_t)1024 * 512 * 2);
    float*    btp = (float*)alloc(1024 * 4);
    _Float16* xT  = (_Float16*)alloc((size_t)2 * THW * CCH * 2);
    _Float16* tpg = (_Float16*)alloc((size_t)2 * THW * 1024 * 2);
    _Float16* g   = (_Float16*)alloc((size_t)2 * DI * THW * 2);
    _Float16* Ot  = (_Float16*)alloc((size_t)2 * THW * DI * 2);
    float*    gnp   = (float*)alloc((size_t)1568 * 2 * 4);
    float*    stats = (float*)alloc(4 * 4);

    const size_t tile_bytes = (size_t)2 * 128 * (THW * 2 + 98 * 4 + 4);
    size_t avail = (ws_size > off + 256) ? ws_size - off - 256 : 0;
    int tiles_fit = (int)(avail / tile_bytes);
    if (tiles_fit < 1) tiles_fit = 1;
    if (tiles_fit > 49) tiles_fit = 49;
    int nch = (49 + tiles_fit - 1) / tiles_fit;
    int tpc = (49 + nch - 1) / nch;

    _Float16* S    = (_Float16*)alloc((size_t)2 * tpc * 128 * THW * 2);
    float*    psum = (float*)alloc((size_t)2 * tpc * 128 * 98 * 4);
    float*    inv  = (float*)alloc((size_t)2 * tpc * 128 * 4);
    _Float16* Opart = (_Float16*)out;   // [8][tpc*128][512] fp16 split-K partials
    _Float16* Pc16  = tpg;              // tpg dead after S-GEMM; reuse

    const size_t sXT = (size_t)THW * CCH;
    const size_t sG  = (size_t)DI * THW;

    pack_weights<<<2048, 256, 0, stream>>>(wt, wp, wg, wo, bt, bp, Wtp, Wg, Wo, btp);
    transpose_cast<<<dim3(THW / 64, CCH / 64, 2), 256, 0, stream>>>(x, xT);

    // theta|phi (t-major): tpg[t, m] = sum_c xT[t,c]*Wtp[m,c] + btp[m]
    gemm_nt<_Float16, 128, false, true, false, false, false><<<8 * 49 * 2, 256, 0, stream>>>(
        xT, CCH, sXT, Wtp, CCH, 0, tpg, 1024, sXT, CCH, CCH, 1.f,
        nullptr, btp, nullptr, nullptr, 0, 0, 8, 49);

    // g (d-major): g[d, t] = sum_c Wg[d,c]*xT[t,c] + bg[d]
    gemm_nt<_Float16, 64, true, false, false, false, false><<<49 * 8 * 2, 256, 0, stream>>>(
        Wg, CCH, 0, xT, CCH, sXT, g, THW, sG, CCH, CCH, 1.f,
        bg, nullptr, nullptr, nullptr, 0, 0, 49, 8);

    // exp2: fold log2(e) into alpha
    const float scale2 = 0.044194173824159216f * 1.4426950408889634f;
    for (int ch = 0; ch < nch; ch++) {
        int tile0 = ch * tpc;
        int tiles = (49 - tile0 < tpc) ? (49 - tile0) : tpc;
        size_t t0 = (size_t)tile0 * 128;
        int tchRows = tiles * 128;
        int stile = (tiles % 7 == 0) ? 7 : 0;   // 7x7 L2 super-tiling

        // expS[t,p] = exp2(scale2 * sum_d theta[t,d]*phi[p,d]); psum partials
        gemm_nt<_Float16, 128, false, false, true, false, false><<<49 * tiles * 2, 256, 0, stream>>>(
            tpg + t0 * 1024, 1024, sXT, tpg + 512, 1024, sXT,
            S, THW, (size_t)tchRows * THW, DI, DI, scale2,
            nullptr, nullptr, psum, nullptr, tchRows, stile, 49, tiles);

        rowsum_inv<<<(2 * tchRows + 255) / 256, 256, 0, stream>>>(psum, inv, 2 * tchRows);

        // Opart[zz][t][d] = inv[t] * sum_{p in split ks} expS[t,p]*g[d,p]
        // split-K=4 (1600,1600,1600,1472 - all %32==0, NT even)
        gemm_nt<_Float16, 128, false, false, false, false, true><<<4 * tiles * 8, 256, 0, stream>>>(
            S, THW, (size_t)tchRows * THW, g, THW, sG,
            Opart, DI, (size_t)tchRows * DI, 1600, THW, 1.f,
            nullptr, nullptr, nullptr, inv, tchRows, 0, 4, tiles);

        // Ot[t,d] = f16( sum_ks Opart[ks*2+n][t][d] )
        combine4<<<(tchRows * 128 + 255) / 256, 256, 0, stream>>>(
            Opart, Ot, tchRows, (int)t0);
    }

    // Pc16[c,t] = f16(sum_d Wo[c,d]*Ot[t,d] + bo[c]); per-block GroupNorm stats
    gemm_nt<_Float16, 128, true, false, false, true, false><<<49 * 8 * 2, 256, 0, stream>>>(
        Wo, DI, 0, Ot, DI, sG, Pc16, THW, (size_t)CCH * THW, DI, DI, 1.f,
        bo, nullptr, gnp, nullptr, 0, 0, 49, 8);

    reduce_final<<<2, 256, 0, stream>>>(gnp, stats, 392);
    final_residual<<<2048, 256, 0, stream>>>(x, Pc16, out, stats, (size_t)2 * CCH * THW / 4);
}

// Round 19
// 376.839 us; speedup vs baseline: 1.6381x; 1.0110x over previous
//
#include <hip/hip_runtime.h>

typedef _Float16 f16x8 __attribute__((ext_vector_type(8)));
typedef _Float16 f16x4 __attribute__((ext_vector_type(4)));
typedef float    f32x4 __attribute__((ext_vector_type(4)));

#define THW 6272
#define CCH 1024
#define DI  512

__device__ __forceinline__ void gload16(const _Float16* g, _Float16* l)
{
    __builtin_amdgcn_global_load_lds(
        (const __attribute__((address_space(1))) void*)g,
        (__attribute__((address_space(3))) void*)l, 16, 0, 0);
}

// ---------------------------------------------------------------------------
// NT GEMM, BK=32 double-buffered counted-vmcnt (perf == R16 single-buf; kept
// for lower bank conflicts). C[M,N] = alpha*A[M,K]*Bt[N,K]^T (+bias).
// BMx128 tile, 4 waves, LDS 2buf x (BM+128)x32 fp16 (32KB @BM=128).
// Flat grid gx*gy*gz, gz = 2*NKS (n=zz&1, ks=zz>>1); split-K slice
// [ks*K, min(ks*K+K,Kfull)); C += zz*sCn.
// stile>0: LxL super-tile decode (L2 working-set tiling).
// YF: by varies fastest (use when the A-slab + full B fit L2; else bx-fastest).
// EXPP: val = exp2(val) (alpha premult by log2e), per-(row,64col) psum.
// GNP: per-block (sum,sumsq). RSC: row scale.
// Regressed variants (do not retry): BM=64-for-PV (R4), BK=64 dbuf 64KB (R6),
// LDS/transposed epilogues (R9/R10/R12), 8-wave (R13), BN=256 (R14),
// counted-vmcnt-as-win (R18: null on 2-phase, matches m233 ceiling).
// ---------------------------------------------------------------------------
template<typename OUT_T, int BM, bool BIAS_M, bool BIAS_N, bool EXPP, bool GNP,
         bool RSC, bool YF>
__global__ __launch_bounds__(256, 4)
void gemm_nt(const _Float16* __restrict__ A, size_t lda, size_t sAn,
             const _Float16* __restrict__ Bt, size_t ldb, size_t sBn,
             OUT_T* __restrict__ C, size_t ldc, size_t sCn,
             int K, int Kfull, float alpha,
             const float* __restrict__ bias_m,
             const float* __restrict__ bias_n,
             float* __restrict__ psum,
             const float* __restrict__ row_scale,
             int rows_ps, int stile,
             int gx, int gy)
{
    constexpr int MF   = BM / 32;
    constexpr int AISS = BM / 64;
    constexpr int ASZ  = BM * 32;
    __shared__ _Float16 As[2 * ASZ];
    __shared__ _Float16 Bs[2 * 4096];
    __shared__ float rs[4], rs2[4];
    const int tid  = threadIdx.x;
    const int lane = tid & 63;
    const int wave = tid >> 6;
    const int wr = wave >> 1, wc = wave & 1;

    // bijective chunked XCD swizzle (m204)
    const int nwg = gridDim.x;
    const int q = nwg >> 3, rr = nwg & 7;
    const int xcd = blockIdx.x & 7, seq = blockIdx.x >> 3;
    const int wg = (xcd < rr ? xcd * (q + 1) : rr * (q + 1) + (xcd - rr) * q) + seq;
    const int zz  = wg / (gx * gy);
    const int rem = wg - zz * gx * gy;
    int by, bx;
    if (stile > 0) {
        const int per = stile * stile;
        const int sgx = gx / stile;
        const int sid = rem / per, wi = rem - sid * per;
        const int srow = sid / sgx, scol = sid - srow * sgx;
        const int wrow = wi / stile;
        by = srow * stile + wrow;
        bx = scol * stile + (wi - wrow * stile);
    } else if (YF) {
        bx = rem / gy; by = rem - bx * gy;   // by (A-tiles) fastest
    } else {
        by = rem / gx; bx = rem - by * gx;   // bx (B-tiles) fastest
    }
    const int n   = zz & 1;
    const int ks  = zz >> 1;

    const int koff = ks * K;
    const int klen = (Kfull - koff < K) ? (Kfull - koff) : K;

    A  += (size_t)n * sAn + (size_t)by * BM * lda + koff;
    Bt += (size_t)n * sBn + (size_t)bx * 128 * ldb + koff;

    const int v0 = tid, v1 = tid + 256;
    const size_t aG0 = (size_t)(v0 >> 2) * lda + (v0 & 3) * 8;
    const size_t aG1 = (size_t)(v1 >> 2) * lda + (v1 & 3) * 8;
    const size_t bG0 = (size_t)(v0 >> 2) * ldb + (v0 & 3) * 8;
    const size_t bG1 = (size_t)(v1 >> 2) * ldb + (v1 & 3) * 8;
    const int lo0 = v0 * 8, lo1 = v1 * 8;

    const int r  = lane & 15;
    const int kg = lane >> 4;

    f32x4 acc[MF][4] = {};

    auto STAGE = [&](int t, int b) {
        const _Float16* a  = A  + (size_t)t * 32;
        const _Float16* bt = Bt + (size_t)t * 32;
        gload16(a + aG0, As + b * ASZ + lo0);
        if constexpr (AISS == 2) gload16(a + aG1, As + b * ASZ + lo1);
        gload16(bt + bG0, Bs + b * 4096 + lo0);
        gload16(bt + bG1, Bs + b * 4096 + lo1);
    };
    auto WAITN = [&]() {
        if constexpr (AISS == 2) asm volatile("s_waitcnt vmcnt(4)" ::: "memory");
        else                     asm volatile("s_waitcnt vmcnt(3)" ::: "memory");
    };
    auto COMPUTE = [&](int b) {
        f16x8 af[MF], bf[4];
#pragma unroll
        for (int mf = 0; mf < MF; mf++)
            af[mf] = *(const f16x8*)(As + b * ASZ + (wr * (BM / 2) + mf * 16 + r) * 32 + kg * 8);
#pragma unroll
        for (int nf = 0; nf < 4; nf++)
            bf[nf] = *(const f16x8*)(Bs + b * 4096 + (wc * 64 + nf * 16 + r) * 32 + kg * 8);
#pragma unroll
        for (int mf = 0; mf < MF; mf++)
#pragma unroll
            for (int nf = 0; nf < 4; nf++)
                acc[mf][nf] = __builtin_amdgcn_mfma_f32_16x16x32_f16(
                    af[mf], bf[nf], acc[mf][nf], 0, 0, 0);
    };

    const int NT = klen >> 5;        // all call-site NT values are even
    STAGE(0, 0);
    for (int it = 0; it < NT; it += 2) {
        STAGE(it + 1, 1);
        WAITN();
        __builtin_amdgcn_s_barrier();
        COMPUTE(0);
        __builtin_amdgcn_s_barrier();
        if (it + 2 < NT) {
            STAGE(it + 2, 0);
            WAITN();
        } else {
            asm volatile("s_waitcnt vmcnt(0)" ::: "memory");
        }
        __builtin_amdgcn_s_barrier();
        COMPUTE(1);
        __builtin_amdgcn_s_barrier();
    }

    C += (size_t)zz * sCn;
    float gs = 0.f, gs2 = 0.f;

#pragma unroll
    for (int mf = 0; mf < MF; mf++) {
#pragma unroll
        for (int qi = 0; qi < 4; qi++) {
            size_t row = (size_t)by * BM + wr * (BM / 2) + mf * 16 + kg * 4 + qi;
            float bm = BIAS_M ? bias_m[row] : 0.f;
            float sc = RSC ? row_scale[(size_t)n * rows_ps + row] : 1.f;
            float rsum = 0.f;
#pragma unroll
            for (int nf = 0; nf < 4; nf++) {
                size_t col = (size_t)bx * 128 + wc * 64 + nf * 16 + r;
                float val = acc[mf][nf][qi] * alpha + bm + (BIAS_N ? bias_n[col] : 0.f);
                if (EXPP) { val = exp2f(val); rsum += val; }
                else if (RSC) val *= sc;
                if (GNP) { gs += val; gs2 += val * val; }
                C[row * ldc + col] = (OUT_T)val;
            }
            if (EXPP) {
                rsum += __shfl_xor(rsum, 1);
                rsum += __shfl_xor(rsum, 2);
                rsum += __shfl_xor(rsum, 4);
                rsum += __shfl_xor(rsum, 8);
                if (r == 0)
                    psum[((size_t)n * rows_ps + row) * 98 + bx * 2 + wc] = rsum;
            }
        }
    }
    if (GNP) {
        for (int o = 32; o; o >>= 1) {
            gs  += __shfl_xor(gs, o);
            gs2 += __shfl_xor(gs2, o);
        }
        if (lane == 0) { rs[wave] = gs; rs2[wave] = gs2; }
        __syncthreads();
        if (tid == 0) {
            psum[(size_t)wg * 2]     = rs[0] + rs[1] + rs[2] + rs[3];
            psum[(size_t)wg * 2 + 1] = rs2[0] + rs2[1] + rs2[2] + rs2[3];
        }
    }
}

// ---------------------------------------------------------------------------
// inv[row] = 1 / sum_chunks psum[row][0..97]
// ---------------------------------------------------------------------------
__global__ __launch_bounds__(256)
void rowsum_inv(const float* __restrict__ psum, float* __restrict__ inv, int nrows)
{
    int rI = blockIdx.x * 256 + threadIdx.x;
    if (rI < nrows) {
        const float* p = psum + (size_t)rI * 98;
        float s = 0.f;
#pragma unroll 7
        for (int i = 0; i < 98; i++) s += p[i];
        inv[rI] = 1.f / s;
    }
}

// ---------------------------------------------------------------------------
// Ot[n][t0+t][d] = f16( sum_{ks=0..3} Op[ks*2+n][t][d] )
// ---------------------------------------------------------------------------
__global__ __launch_bounds__(256)
void combine4(const _Float16* __restrict__ Op, _Float16* __restrict__ Ot,
              int tr, int t0)
{
    const int per_n8 = tr * 64;
    int idx = blockIdx.x * 256 + threadIdx.x;
    if (idx >= 2 * per_n8) return;
    int n = idx / per_n8;
    int rem = idx - n * per_n8;
    int t = rem >> 6, d8 = rem & 63;
    const size_t slice = (size_t)tr * 512;
    float o[8] = {};
#pragma unroll
    for (int ks = 0; ks < 4; ks++) {
        f16x8 v = *(const f16x8*)(Op + (size_t)(ks * 2 + n) * slice + (size_t)rem * 8);
#pragma unroll
        for (int j = 0; j < 8; j++) o[j] += (float)v[j];
    }
    f16x8 w;
#pragma unroll
    for (int j = 0; j < 8; j++) w[j] = (_Float16)o[j];
    *(f16x8*)(Ot + ((size_t)(n * THW + t0 + t) * DI + d8 * 8)) = w;
}

// ---------------------------------------------------------------------------
__global__ __launch_bounds__(256)
void pack_weights(const float* __restrict__ wt, const float* __restrict__ wp,
                  const float* __restrict__ wg, const float* __restrict__ wo,
                  const float* __restrict__ bt, const float* __restrict__ bp,
                  _Float16* __restrict__ Wtp, _Float16* __restrict__ Wg,
                  _Float16* __restrict__ Wo, float* __restrict__ btp)
{
    int i = blockIdx.x * 256 + threadIdx.x;
    if (i < 512 * 1024) {
        Wtp[i]              = (_Float16)wt[i];
        Wtp[i + 512 * 1024] = (_Float16)wp[i];
        Wg[i]               = (_Float16)wg[i];
        Wo[i]               = (_Float16)wo[i];
    }
    if (i < 512) { btp[i] = bt[i]; btp[i + 512] = bp[i]; }
}

// ---------------------------------------------------------------------------
// xT[n, t, c] = f16(x[n, c, t])  — 64x64 tile, f16x8 vector stores.
// ---------------------------------------------------------------------------
__global__ __launch_bounds__(256)
void transpose_cast(const float* __restrict__ x, _Float16* __restrict__ xT)
{
    __shared__ float tile[64][65];
    const int n  = blockIdx.z;
    const int t0 = blockIdx.x * 64;
    const int c0 = blockIdx.y * 64;
    const int tid = threadIdx.x;
    const float* xp = x + ((size_t)n * CCH + c0) * THW + t0;
#pragma unroll
    for (int i = 0; i < 16; i++) {
        int v = tid + i * 256;
        int c = v >> 6, t = v & 63;
        tile[t][c] = xp[(size_t)c * THW + t];
    }
    __syncthreads();
    _Float16* op = xT + ((size_t)n * THW + t0) * CCH + c0;
#pragma unroll
    for (int i = 0; i < 2; i++) {
        int v = tid + i * 256;
        int t = v >> 3, c8 = (v & 7) * 8;
        f16x8 o;
#pragma unroll
        for (int j = 0; j < 8; j++) o[j] = (_Float16)tile[t][c8 + j];
        *(f16x8*)(op + (size_t)t * CCH + c8) = o;
    }
}

// ---------------------------------------------------------------------------
// GroupNorm finalize from per-block partials + fused residual.
// ---------------------------------------------------------------------------
__global__ __launch_bounds__(256)
void reduce_final(const float* __restrict__ partials, float* __restrict__ stats, int nblk)
{
    const int n = blockIdx.x;
    float s = 0.f, s2 = 0.f;
    for (int i = threadIdx.x; i < nblk; i += 256) {
        s  += partials[((size_t)n * nblk + i) * 2];
        s2 += partials[((size_t)n * nblk + i) * 2 + 1];
    }
    for (int o = 32; o; o >>= 1) { s += __shfl_xor(s, o); s2 += __shfl_xor(s2, o); }
    __shared__ float rs[4], rs2[4];
    if ((threadIdx.x & 63) == 0) { rs[threadIdx.x >> 6] = s; rs2[threadIdx.x >> 6] = s2; }
    __syncthreads();
    if (threadIdx.x == 0) {
        float S1 = rs[0] + rs[1] + rs[2] + rs[3];
        float S2 = rs2[0] + rs2[1] + rs2[2] + rs2[3];
        const float invc = 1.f / ((float)CCH * (float)THW);
        float mean = S1 * invc;
        float var  = S2 * invc - mean * mean;
        stats[n * 2]     = mean;
        stats[n * 2 + 1] = rsqrtf(var + 1e-5f);
    }
}

// out[i] = x[i] + (pc16[i] - mean) * rstd
__global__ __launch_bounds__(256)
void final_residual(const float* __restrict__ x, const _Float16* __restrict__ pc16,
                    float* __restrict__ outp, const float* __restrict__ stats,
                    size_t total4)
{
    const size_t per_n4 = (size_t)CCH * THW / 4;
    for (size_t i = (size_t)blockIdx.x * 256 + threadIdx.x; i < total4;
         i += (size_t)gridDim.x * 256) {
        int n = (int)(i / per_n4);
        float mean = stats[n * 2], rstd = stats[n * 2 + 1];
        f32x4 xv = ((const f32x4*)x)[i];
        f16x4 pv = ((const f16x4*)pc16)[i];
        f32x4 ov;
#pragma unroll
        for (int j = 0; j < 4; j++) ov[j] = xv[j] + ((float)pv[j] - mean) * rstd;
        ((f32x4*)outp)[i] = ov;
    }
}

// ---------------------------------------------------------------------------
extern "C" void kernel_launch(void* const* d_in, const int* in_sizes, int n_in,
                              void* d_out, int out_size, void* d_ws, size_t ws_size,
                              hipStream_t stream)
{
    const float* x  = (const float*)d_in[0];
    const float* wt = (const float*)d_in[1];
    const float* bt = (const float*)d_in[2];
    const float* wp = (const float*)d_in[3];
    const float* bp = (const float*)d_in[4];
    const float* wg = (const float*)d_in[5];
    const float* bg = (const float*)d_in[6];
    const float* wo = (const float*)d_in[7];
    const float* bo = (const float*)d_in[8];
    float* out = (float*)d_out;

    char* ws = (char*)d_ws;
    size_t off = 0;
    auto alloc = [&](size_t b) -> void* {
        off = (off + 255) & ~(size_t)255;
        void* p = ws + off;
        off += b;
        return p;
    };

    _Float16* Wtp = (_Float16*)alloc((size_t)1024 * 1024 * 2);
    _Float16* Wg  = (_Float16*)alloc((size_t)512 * 1024 * 2);
    _Float16* Wo  = (_Float16*)alloc((size_t)1024 * 512 * 2);
    float*    btp = (float*)alloc(1024 * 4);
    _Float16* xT  = (_Float16*)alloc((size_t)2 * THW * CCH * 2);
    _Float16* tpg = (_Float16*)alloc((size_t)2 * THW * 1024 * 2);
    _Float16* g   = (_Float16*)alloc((size_t)2 * DI * THW * 2);
    _Float16* Ot  = (_Float16*)alloc((size_t)2 * THW * DI * 2);
    float*    gnp   = (float*)alloc((size_t)1568 * 2 * 4);
    float*    stats = (float*)alloc(4 * 4);

    const size_t tile_bytes = (size_t)2 * 128 * (THW * 2 + 98 * 4 + 4);
    size_t avail = (ws_size > off + 256) ? ws_size - off - 256 : 0;
    int tiles_fit = (int)(avail / tile_bytes);
    if (tiles_fit < 1) tiles_fit = 1;
    if (tiles_fit > 49) tiles_fit = 49;
    int nch = (49 + tiles_fit - 1) / tiles_fit;
    int tpc = (49 + nch - 1) / nch;

    _Float16* S    = (_Float16*)alloc((size_t)2 * tpc * 128 * THW * 2);
    float*    psum = (float*)alloc((size_t)2 * tpc * 128 * 98 * 4);
    float*    inv  = (float*)alloc((size_t)2 * tpc * 128 * 4);
    _Float16* Opart = (_Float16*)out;   // [8][tpc*128][512] fp16 split-K partials
    _Float16* Pc16  = tpg;              // tpg dead after S-GEMM; reuse

    const size_t sXT = (size_t)THW * CCH;
    const size_t sG  = (size_t)DI * THW;

    pack_weights<<<2048, 256, 0, stream>>>(wt, wp, wg, wo, bt, bp, Wtp, Wg, Wo, btp);
    transpose_cast<<<dim3(THW / 64, CCH / 64, 2), 256, 0, stream>>>(x, xT);

    // theta|phi (t-major): bx-fastest already ideal (8 Wtp-tiles share xT slab)
    gemm_nt<_Float16, 128, false, true, false, false, false, false><<<8 * 49 * 2, 256, 0, stream>>>(
        xT, CCH, sXT, Wtp, CCH, 0, tpg, 1024, sXT, CCH, CCH, 1.f,
        nullptr, btp, nullptr, nullptr, 0, 0, 8, 49);

    // g (d-major): YF — 8 d-tiles (by) consecutive share one xT col-slab;
    // Wg (1MB) recurs in L2.
    gemm_nt<_Float16, 64, true, false, false, false, false, true><<<49 * 8 * 2, 256, 0, stream>>>(
        Wg, CCH, 0, xT, CCH, sXT, g, THW, sG, CCH, CCH, 1.f,
        bg, nullptr, nullptr, nullptr, 0, 0, 49, 8);

    // exp2: fold log2(e) into alpha
    const float scale2 = 0.044194173824159216f * 1.4426950408889634f;
    for (int ch = 0; ch < nch; ch++) {
        int tile0 = ch * tpc;
        int tiles = (49 - tile0 < tpc) ? (49 - tile0) : tpc;
        size_t t0 = (size_t)tile0 * 128;
        int tchRows = tiles * 128;
        int stile = (tiles % 7 == 0) ? 7 : 0;   // 7x7 L2 super-tiling

        // expS[t,p] = exp2(scale2 * sum_d theta[t,d]*phi[p,d]); psum partials
        gemm_nt<_Float16, 128, false, false, true, false, false, false><<<49 * tiles * 2, 256, 0, stream>>>(
            tpg + t0 * 1024, 1024, sXT, tpg + 512, 1024, sXT,
            S, THW, (size_t)tchRows * THW, DI, DI, scale2,
            nullptr, nullptr, psum, nullptr, tchRows, stile, 49, tiles);

        rowsum_inv<<<(2 * tchRows + 255) / 256, 256, 0, stream>>>(psum, inv, 2 * tchRows);

        // PV: bx-fastest already ideal (4 d-tiles share one S row-slab)
        gemm_nt<_Float16, 128, false, false, false, false, true, false><<<4 * tiles * 8, 256, 0, stream>>>(
            S, THW, (size_t)tchRows * THW, g, THW, sG,
            Opart, DI, (size_t)tchRows * DI, 1600, THW, 1.f,
            nullptr, nullptr, nullptr, inv, tchRows, 0, 4, tiles);

        combine4<<<(tchRows * 128 + 255) / 256, 256, 0, stream>>>(
            Opart, Ot, tchRows, (int)t0);
    }

    // out: YF — 8 c-tiles (by) consecutive share one Ot slab (128KB);
    // Wo (1MB) recurs in L2. GNP stats fused.
    gemm_nt<_Float16, 128, true, false, false, true, false, true><<<49 * 8 * 2, 256, 0, stream>>>(
        Wo, DI, 0, Ot, DI, sG, Pc16, THW, (size_t)CCH * THW, DI, DI, 1.f,
        bo, nullptr, gnp, nullptr, 0, 0, 49, 8);

    reduce_final<<<2, 256, 0, stream>>>(gnp, stats, 392);
    final_residual<<<2048, 256, 0, stream>>>(x, Pc16, out, stats, (size_t)2 * CCH * THW / 4);
}